// Round 9
// baseline (407.666 us; speedup 1.0000x reference)
//
#include <hip/hip_runtime.h>

#define SN 6400      // H*W
#define CN 256       // channels (= GEMM K)
#define NBATCH 2
#define NTILES 25    // SN / 256 (fixed-side row tiles)
#define NCHUNK 5     // streamed-side chunks (grid = 25*5*2 = 250 blocks, 1/CU)
#define TPC 5        // 256-wide streamed tiles per chunk
#define NSTG (TPC*4) // 20 stages per block (BK=64 per stage)

typedef _Float16 f16;
typedef f16 f16x8 __attribute__((ext_vector_type(8)));
typedef f16 f16x4 __attribute__((ext_vector_type(4)));
typedef float f32x4 __attribute__((ext_vector_type(4)));

__device__ __forceinline__ void gld16(const f16* g, f16* l) {
    __builtin_amdgcn_global_load_lds(
        (__attribute__((address_space(1))) void*)(g),
        (__attribute__((address_space(3))) void*)(l), 16, 0, 0);
}

// Stage a 256-row x 64-half (32 KB) region into LDS with 512 threads
// (4 gld16/thread). LDS row = 64 halfs = 128 B = 8 x 16B chunks; LDS chunk c
// holds global chunk c ^ (row&7) (swizzle on SOURCE address; DMA lane->LDS
// map fixed). Verified conflict-free (R0-R8: SQ_LDS_BANK_CONFLICT = 0).
__device__ __forceinline__ void stage64(const f16* __restrict__ g,
                                        f16* l, int tid) {
    #pragma unroll
    for (int it = 0; it < 4; ++it) {
        int q = it * 512 + tid;
        int row = q >> 3, c = q & 7;
        int cg = c ^ (row & 7);
        gld16(g + (size_t)row * CN + cg * 8, l + (q & ~63) * 8);
    }
}

// ---------------- prep kernels (unchanged) ----------------

__global__ __launch_bounds__(256) void k_meanT(const float* __restrict__ T,
                                               float* __restrict__ meanT) {
    int c = blockIdx.x, t = threadIdx.x;
    const float* p0 = T + (size_t)c * SN;
    const float* p1 = T + (size_t)(CN + c) * SN;
    float s = 0.f;
    for (int i = t; i < SN; i += 256) s += p0[i] + p1[i];
    #pragma unroll
    for (int d = 1; d < 64; d <<= 1) s += __shfl_xor(s, d, 64);
    __shared__ float sb[4];
    if ((t & 63) == 0) sb[t >> 6] = s;
    __syncthreads();
    if (t == 0) meanT[c] = (sb[0] + sb[1] + sb[2] + sb[3]) * (1.0f / 12800.0f);
}

// transpose [n,c,s] -> [n,s,c], center, cast to fp16 (normalized by k_nrm)
__global__ __launch_bounds__(256) void k_xpose(const float* __restrict__ X,
                                               const float* __restrict__ meanT,
                                               f16* __restrict__ out) {
    int n = blockIdx.z, c0 = blockIdx.y * 32, s0 = blockIdx.x * 64;
    __shared__ float tile[32][65];
    int tx = threadIdx.x & 63, ty = threadIdx.x >> 6;
    const float* Xb = X + ((size_t)n * CN + c0) * SN + s0;
    #pragma unroll
    for (int cy = ty; cy < 32; cy += 4)
        tile[cy][tx] = Xb[(size_t)cy * SN + tx] - meanT[c0 + cy];
    __syncthreads();
    int cc = threadIdx.x & 31, sy = threadIdx.x >> 5;
    f16* ob = out + ((size_t)n * SN + s0) * CN + c0;
    #pragma unroll
    for (int sr = sy; sr < 64; sr += 8)
        ob[(size_t)sr * CN + cc] = (f16)tile[cc][sr];
}

// fused: per-row sum-of-squares -> rsqrt -> in-place scale (one wave per row)
__global__ __launch_bounds__(256) void k_nrm(f16* __restrict__ Ah,
                                             f16* __restrict__ Bh) {
    int w = threadIdx.x >> 6, lane = threadIdx.x & 63;
    int idx = blockIdx.x * 4 + w;
    f16x4* pa = (f16x4*)(Ah + (size_t)idx * CN + lane * 4);
    f16x4* pb = (f16x4*)(Bh + (size_t)idx * CN + lane * 4);
    f16x4 a = *pa, b = *pb;
    float sa = 0.f, sb = 0.f;
    #pragma unroll
    for (int j = 0; j < 4; ++j) {
        float x = (float)a[j]; sa += x * x;
        float y = (float)b[j]; sb += y * y;
    }
    #pragma unroll
    for (int d = 1; d < 64; d <<= 1) {
        sa += __shfl_xor(sa, d, 64);
        sb += __shfl_xor(sb, d, 64);
    }
    float ra = rsqrtf(sa), rb = rsqrtf(sb);
    #pragma unroll
    for (int j = 0; j < 4; ++j) {
        a[j] = (f16)((float)a[j] * ra);
        b[j] = (f16)((float)b[j] * rb);
    }
    *pa = a; *pb = b;
}

// ---------------- fused GEMM passes ----------------
// R9 = R8 with the register clamp removed: __launch_bounds__(512) (NO
// min-waves arg). Evidence R2/R4/R8: a second arg of 2 clamps the allocator
// to 128 VGPR and spills (WRITE_SIZE 85-208 MB); block size alone implies
// 2 waves/SIMD -> 256 reg/wave budget (unified VGPR+AGPR), which fits this
// body (~230: acc 128 in AGPRs + frags 48 + addressing).
// Geometry: 512 thr (8 waves, 2Mx4N), block tile 256x256, wave tile 128x64
// (acc 8x4 f32x4), BK=64, both A and B streamed per stage into a 64 KB
// combined buffer [A 32K | B 32K], double-buffered (128 KB LDS, 1 block/CU,
// buf index literal). Per stage: COMPUTE(buf) -> BAR -> issue DMA(s+2) into
// the just-read buf -> WAIT vmcnt(8) (drains DMA(s+1), leaves DMA(s+2)) ->
// BAR. 64 MFMA + 24 ds_read_b128 per wave-stage = 2x R3's work per
// barrier-pair (R0-R8 evidence: sync dead-time per stage is ~constant, so
// work/stage is the lever). PASS1 per-row g lives in a 1 KB LDS table
// (read via ds_read in the epilogue -> off the vmcnt ledger).
// PASS 0: per-row max of cos                          (fixed = I rows i)
// PASS 1: per-row sum of exp((10 - g_i*raw)/ln2)      (fixed = I rows i)
// PASS 2: per-row max over cols of (alpha_c - g_c*raw)(fixed = T rows j)
template <int PASS>
__global__ __launch_bounds__(512) void k_gemm(const f16* __restrict__ A,
                                              const f16* __restrict__ B,
                                              const float* __restrict__ grow,
                                              const float* __restrict__ alpha,
                                              float* __restrict__ outP) {
    const int n = blockIdx.z, chunk = blockIdx.y, ft = blockIdx.x;
    const int tid = threadIdx.x, lane = tid & 63, wv = tid >> 6;
    const int wr = wv >> 2, wc = wv & 3, quad = lane >> 4, lrow = lane & 15;

    __shared__ f16 Sb[2][32768];    // 2 x 64 KB: [A 16384 halfs | B 16384]
    __shared__ float gldt[256];     // PASS1: per-row g table (1 KB)

    const f16* At = A + ((size_t)n * SN + (size_t)ft * 256) * CN;
    const f16* Bc = B + ((size_t)n * SN + (size_t)chunk * (TPC * 256)) * CN;

    // PASS1: stage the block's 256 per-row g values into LDS (one-time).
    if constexpr (PASS == 1) {
        if (tid < 256) gldt[tid] = grow[(size_t)n * SN + ft * 256 + tid];
        asm volatile("s_waitcnt lgkmcnt(0)" ::: "memory");
    }

    // ---- prologue: DMA stages 0 and 1 (A slice + B slice each) ----
    stage64(At,      Sb[0],         tid);   // s0 A (K 0..64)
    stage64(Bc,      Sb[0] + 16384, tid);   // s0 B (tile 0)
    stage64(At + 64, Sb[1],         tid);   // s1 A (K 64..128)
    stage64(Bc + 64, Sb[1] + 16384, tid);   // s1 B

    // per-lane LDS frag offsets (halfs). ra = wr*128 + mt*16 + lrow has
    // (ra&7)==(lrow&7) -> swizzle term mt-independent: frag mt at off + mt*1024.
    int offA[2], offB[2];
    #pragma unroll
    for (int kk = 0; kk < 2; ++kk) {
        int swz = ((kk * 4 + quad) ^ (lrow & 7)) * 8;
        offA[kk] = (wr * 128 + lrow) * 64 + swz;
        offB[kk] = 16384 + (wc * 64 + lrow) * 64 + swz;
    }

    float runRow[8][4];
    #pragma unroll
    for (int mt = 0; mt < 8; ++mt)
        #pragma unroll
        for (int v = 0; v < 4; ++v) runRow[mt][v] = (PASS == 1) ? 0.f : -3.0e38f;

    float gl[4], al[4];
    const float L2E = 1.44269504089f;
    const float TENL2E = 14.4269504089f;

    // outstanding: s0(8) + s1(8); vmcnt(8) drains s0
    asm volatile("s_waitcnt vmcnt(8)" ::: "memory");
    __builtin_amdgcn_s_barrier();

#define BAR()    __builtin_amdgcn_s_barrier()
#define WAIT8()  asm volatile("s_waitcnt vmcnt(8)" ::: "memory")
#define WAIT16() asm volatile("s_waitcnt vmcnt(16)" ::: "memory")
#define WAIT0()  asm volatile("s_waitcnt vmcnt(0)" ::: "memory")

// one BK=64 stage from Sb[BUF] (literal): 16+8 ds_read_b128, 64 MFMA
#define COMPUTE(BUF)                                                        \
    { _Pragma("unroll")                                                     \
      for (int kk = 0; kk < 2; ++kk) {                                      \
          f16x8 af[8]; f16x8 bf[4];                                         \
          _Pragma("unroll")                                                 \
          for (int mt = 0; mt < 8; ++mt)                                    \
              af[mt] = *(const f16x8*)&Sb[BUF][offA[kk] + mt * 1024];       \
          _Pragma("unroll")                                                 \
          for (int nt = 0; nt < 4; ++nt)                                    \
              bf[nt] = *(const f16x8*)&Sb[BUF][offB[kk] + nt * 1024];       \
          __builtin_amdgcn_s_setprio(1);                                    \
          _Pragma("unroll")                                                 \
          for (int mt = 0; mt < 8; ++mt)                                    \
              _Pragma("unroll")                                             \
              for (int nt = 0; nt < 4; ++nt)                                \
                  acc[mt][nt] = __builtin_amdgcn_mfma_f32_16x16x32_f16(     \
                      af[mt], bf[nt], acc[mt][nt], 0, 0, 0);                \
          __builtin_amdgcn_s_setprio(0);                                    \
      } }

#define ZEROACC()                                                           \
    { _Pragma("unroll")                                                     \
      for (int mt = 0; mt < 8; ++mt)                                        \
          _Pragma("unroll")                                                 \
          for (int nt = 0; nt < 4; ++nt)                                    \
              acc[mt][nt] = (f32x4){0.f, 0.f, 0.f, 0.f}; }

// per-tile epilogue (acc complete). PASS1 reads g from LDS (lgkm, not vmcnt).
#define EPILOGUE()                                                          \
    if constexpr (PASS == 0) {                                              \
        _Pragma("unroll")                                                   \
        for (int mt = 0; mt < 8; ++mt)                                      \
            _Pragma("unroll")                                               \
            for (int v = 0; v < 4; ++v) {                                   \
                float m = fmaxf(fmaxf(acc[mt][0][v], acc[mt][1][v]),        \
                                fmaxf(acc[mt][2][v], acc[mt][3][v]));       \
                runRow[mt][v] = fmaxf(runRow[mt][v], m);                    \
            }                                                               \
    } else if constexpr (PASS == 1) {                                       \
        _Pragma("unroll")                                                   \
        for (int mt = 0; mt < 8; ++mt) {                                    \
            f32x4 gv = *(const f32x4*)&gldt[wr * 128 + mt * 16 + quad * 4]; \
            _Pragma("unroll")                                               \
            for (int v = 0; v < 4; ++v) {                                   \
                float c1 = 0.5f * gv[v] * L2E;                              \
                float a0 = TENL2E - c1;                                     \
                float s2 = runRow[mt][v];                                   \
                _Pragma("unroll")                                           \
                for (int nt = 0; nt < 4; ++nt) {                            \
                    float arg = fminf(TENL2E,                               \
                                      fmaf(acc[mt][nt][v], c1, a0));        \
                    s2 += exp2f(arg);                                       \
                }                                                           \
                runRow[mt][v] = s2;                                         \
            }                                                               \
        }                                                                   \
    } else {                                                                \
        _Pragma("unroll")                                                   \
        for (int mt = 0; mt < 8; ++mt)                                      \
            _Pragma("unroll")                                               \
            for (int v = 0; v < 4; ++v) {                                   \
                _Pragma("unroll")                                           \
                for (int nt = 0; nt < 4; ++nt) {                            \
                    float raw = fmaxf(0.f,                                  \
                        fmaf(acc[mt][nt][v], -0.5f, 0.5f));                 \
                    float lc = fmaf(-gl[nt], raw, al[nt]);                  \
                    runRow[mt][v] = fmaxf(runRow[mt][v], lc);               \
                }                                                           \
            }                                                               \
    }

    f32x4 acc[8][4];

    // ---- main loop: t = 0..TPC-2, 4 literal-ks stages each ----
    #pragma unroll 1
    for (int t = 0; t < TPC - 1; ++t) {
        const f16* Bt = Bc + (size_t)t * (256 * CN);
        const f16* Bn = Bt + 256 * CN;

        ZEROACC();

        // ks0 (stage 4t, buf0)
        COMPUTE(0)
        BAR();
        stage64(At + 128, Sb[0], tid);            // DMA(4t+2) A (K 128..192)
        stage64(Bt + 128, Sb[0] + 16384, tid);    // DMA(4t+2) B
        if constexpr (PASS == 2) {
            #pragma unroll
            for (int nt = 0; nt < 4; ++nt) {
                int i = (chunk * TPC + t) * 256 + wc * 64 + nt * 16 + lrow;
                gl[nt] = grow[(size_t)n * SN + i];
                al[nt] = alpha[(size_t)n * SN + i];
            }
            WAIT16();   // drains DMA(4t+1) only (coeffs+DMA(4t+2) younger)
        } else {
            WAIT8();
        }
        BAR();

        // ks1 (stage 4t+1, buf1)
        COMPUTE(1)
        BAR();
        stage64(At + 192, Sb[1], tid);            // DMA(4t+3) A (K 192..256)
        stage64(Bt + 192, Sb[1] + 16384, tid);    // DMA(4t+3) B
        WAIT8();
        BAR();

        // ks2 (stage 4t+2, buf0)
        COMPUTE(0)
        BAR();
        stage64(At, Sb[0], tid);                  // DMA(4t+4): tile t+1, K 0..64
        stage64(Bn, Sb[0] + 16384, tid);
        WAIT8();
        BAR();

        // ks3 (stage 4t+3, buf1)
        COMPUTE(1)
        BAR();
        stage64(At + 64, Sb[1], tid);             // DMA(4t+5): tile t+1, K 64..128
        stage64(Bn + 64, Sb[1] + 16384, tid);
        EPILOGUE()                                 // overlaps in-flight DMA
        WAIT8();
        BAR();
    }

    // ---- peeled last tile (t = TPC-1): drain ----
    {
        const int t = TPC - 1;
        const f16* Bt = Bc + (size_t)t * (256 * CN);

        ZEROACC();

        COMPUTE(0)                                 // stage 16
        BAR();
        stage64(At + 128, Sb[0], tid);             // DMA(18)
        stage64(Bt + 128, Sb[0] + 16384, tid);
        if constexpr (PASS == 2) {
            #pragma unroll
            for (int nt = 0; nt < 4; ++nt) {
                int i = (chunk * TPC + t) * 256 + wc * 64 + nt * 16 + lrow;
                gl[nt] = grow[(size_t)n * SN + i];
                al[nt] = alpha[(size_t)n * SN + i];
            }
            WAIT16();
        } else {
            WAIT8();
        }
        BAR();

        COMPUTE(1)                                 // stage 17
        BAR();
        stage64(At + 192, Sb[1], tid);             // DMA(19)
        stage64(Bt + 192, Sb[1] + 16384, tid);
        WAIT8();
        BAR();

        COMPUTE(0)                                 // stage 18
        WAIT0();                                   // drain DMA(19)
        BAR();

        COMPUTE(1)                                 // stage 19
        EPILOGUE()
    }
#undef COMPUTE
#undef ZEROACC
#undef EPILOGUE
#undef BAR
#undef WAIT8
#undef WAIT16
#undef WAIT0

    // ---- cross-lane / cross-wave reduction (red aliased onto Sb) ----
    __syncthreads();                 // all waves done with Sb
    float* red = (float*)&Sb[0][0];
    #pragma unroll
    for (int mt = 0; mt < 8; ++mt)
        #pragma unroll
        for (int v = 0; v < 4; ++v) {
            float val = runRow[mt][v];
            #pragma unroll
            for (int d = 1; d < 16; d <<= 1) {
                float o = __shfl_xor(val, d, 64);
                val = (PASS == 1) ? (val + o) : fmaxf(val, o);
            }
            if (lrow == 0)
                red[wc * 256 + wr * 128 + mt * 16 + quad * 4 + v] = val;
        }
    __syncthreads();
    if (tid < 256) {
        float a = red[tid], b = red[256 + tid];
        float c = red[512 + tid], d = red[768 + tid];
        float r = (PASS == 1) ? (a + b + c + d)
                              : fmaxf(fmaxf(a, b), fmaxf(c, d));
        outP[(size_t)(n * NCHUNK + chunk) * SN + ft * 256 + tid] = r;
    }
}

// ---------------- small reduce kernels (unchanged) ----------------

__global__ __launch_bounds__(256) void r_g(const float* __restrict__ rowmaxP,
                                           float* __restrict__ grow) {
    int idx = blockIdx.x * 256 + threadIdx.x;
    int n = idx / SN, i = idx - n * SN;
    float m = -3.0e38f;
    for (int ch = 0; ch < NCHUNK; ++ch)
        m = fmaxf(m, rowmaxP[(size_t)(n * NCHUNK + ch) * SN + i]);
    float mr = fmaxf(0.f, (1.f - m) * 0.5f);
    grow[idx] = 10.f / (mr + 1e-5f);
}

__global__ __launch_bounds__(256) void r_alpha(const float* __restrict__ rowsumP,
                                               float* __restrict__ alpha) {
    int idx = blockIdx.x * 256 + threadIdx.x;
    int n = idx / SN, i = idx - n * SN;
    float s = 0.f;
    for (int ch = 0; ch < NCHUNK; ++ch)
        s += rowsumP[(size_t)(n * NCHUNK + ch) * SN + i];
    alpha[idx] = 10.f - logf(s);
}

__global__ __launch_bounds__(256) void r_colfin(const float* __restrict__ colmaxP,
                                                float* __restrict__ bsum) {
    int idx = blockIdx.x * 256 + threadIdx.x;
    int n = idx / SN, j = idx - n * SN;
    float m = -3.0e38f;
    for (int ch = 0; ch < NCHUNK; ++ch)
        m = fmaxf(m, colmaxP[(size_t)(n * NCHUNK + ch) * SN + j]);
    float v = expf(m);
    #pragma unroll
    for (int d = 1; d < 64; d <<= 1) v += __shfl_xor(v, d, 64);
    __shared__ float sb[4];
    if ((threadIdx.x & 63) == 0) sb[threadIdx.x >> 6] = v;
    __syncthreads();
    if (threadIdx.x == 0) bsum[blockIdx.x] = sb[0] + sb[1] + sb[2] + sb[3];
}

__global__ __launch_bounds__(64) void r_loss(const float* __restrict__ bsum,
                                             float* __restrict__ out) {
    int t = threadIdx.x;
    float v = (t < 50) ? bsum[t] : 0.f;
    float v0 = (t < 25) ? v : 0.f;
    float v1 = (t >= 25 && t < 50) ? v : 0.f;
    #pragma unroll
    for (int d = 1; d < 64; d <<= 1) {
        v0 += __shfl_xor(v0, d, 64);
        v1 += __shfl_xor(v1, d, 64);
    }
    if (t == 0) {
        float cs0 = v0 * (1.0f / SN), cs1 = v1 * (1.0f / SN);
        out[0] = -0.5f * (logf(cs0) + logf(cs1));
    }
}

// ---------------- launch ----------------

extern "C" void kernel_launch(void* const* d_in, const int* in_sizes, int n_in,
                              void* d_out, int out_size, void* d_ws, size_t ws_size,
                              hipStream_t stream) {
    const float* I = (const float*)d_in[0];
    const float* T = (const float*)d_in[1];
    float* out = (float*)d_out;

    float* wsf = (float*)d_ws;
    float* meanT = wsf;                        // 256
    float* grow  = meanT + 256;                // 12800
    float* alpha = grow + 12800;               // 12800
    float* rowmaxP = alpha + 12800;            // 64000
    float* rowsumP = rowmaxP + 64000;          // 64000
    float* colmaxP = rowsumP + 64000;          // 64000
    float* bsum = colmaxP + 64000;             // 64
    f16* Ah = (f16*)(bsum + 64);               // 2*6400*256 fp16 (centered I, [n,s,c])
    f16* Bh = Ah + (size_t)NBATCH * SN * CN;   // centered T; total ws ~14.1 MB

    k_meanT<<<256, 256, 0, stream>>>(T, meanT);
    k_xpose<<<dim3(100, 8, 2), 256, 0, stream>>>(I, meanT, Ah);
    k_xpose<<<dim3(100, 8, 2), 256, 0, stream>>>(T, meanT, Bh);
    k_nrm<<<3200, 256, 0, stream>>>(Ah, Bh);

    dim3 gg(NTILES, NCHUNK, NBATCH);
    k_gemm<0><<<gg, 512, 0, stream>>>(Ah, Bh, nullptr, nullptr, rowmaxP);
    r_g<<<50, 256, 0, stream>>>(rowmaxP, grow);
    k_gemm<1><<<gg, 512, 0, stream>>>(Ah, Bh, grow, nullptr, rowsumP);
    r_alpha<<<50, 256, 0, stream>>>(rowsumP, alpha);
    k_gemm<2><<<gg, 512, 0, stream>>>(Bh, Ah, grow, alpha, colmaxP);
    r_colfin<<<50, 256, 0, stream>>>(colmaxP, bsum);
    r_loss<<<1, 64, 0, stream>>>(bsum, out);
}

// Round 10
// 249.707 us; speedup vs baseline: 1.6326x; 1.6326x over previous
//
#include <hip/hip_runtime.h>

#define SN 6400      // H*W
#define CN 256       // channels (= GEMM K)
#define NBATCH 2
#define NTILES 50    // SN / 128 (fixed-side row tiles, GEMM)
#define NCHUNK 5     // streamed-side chunks (GEMM grid = 50*5*2 = 500 blocks)
#define TPC 5        // 256-wide streamed tiles per chunk
#define NSTG (TPC*4) // 20 stages per block (BK=64 per stage)
#define NJC 16       // pass1 j-chunks (6400/400)
#define NIP 25       // i/j panels of 256

typedef _Float16 f16;
typedef f16 f16x8 __attribute__((ext_vector_type(8)));
typedef f16 f16x4 __attribute__((ext_vector_type(4)));
typedef float f32x4 __attribute__((ext_vector_type(4)));

__device__ __forceinline__ void gld16(const f16* g, f16* l) {
    __builtin_amdgcn_global_load_lds(
        (__attribute__((address_space(1))) void*)(g),
        (__attribute__((address_space(3))) void*)(l), 16, 0, 0);
}

// Stage a 256-row x 64-half (32 KB) K-chunk into LDS with 512 threads
// (4 gld16/thread). XOR source swizzle; verified conflict-free (R0-R9).
__device__ __forceinline__ void stageB(const f16* __restrict__ g,
                                       f16* l, int tid) {
    #pragma unroll
    for (int it = 0; it < 4; ++it) {
        int q = it * 512 + tid;
        int row = q >> 3, c = q & 7;
        int cg = c ^ (row & 7);
        gld16(g + (size_t)row * CN + cg * 8, l + (q & ~63) * 8);
    }
}

// ---------------- prep kernels (unchanged) ----------------

__global__ __launch_bounds__(256) void k_meanT(const float* __restrict__ T,
                                               float* __restrict__ meanT) {
    int c = blockIdx.x, t = threadIdx.x;
    const float* p0 = T + (size_t)c * SN;
    const float* p1 = T + (size_t)(CN + c) * SN;
    float s = 0.f;
    for (int i = t; i < SN; i += 256) s += p0[i] + p1[i];
    #pragma unroll
    for (int d = 1; d < 64; d <<= 1) s += __shfl_xor(s, d, 64);
    __shared__ float sb[4];
    if ((t & 63) == 0) sb[t >> 6] = s;
    __syncthreads();
    if (t == 0) meanT[c] = (sb[0] + sb[1] + sb[2] + sb[3]) * (1.0f / 12800.0f);
}

__global__ __launch_bounds__(256) void k_xpose(const float* __restrict__ X,
                                               const float* __restrict__ meanT,
                                               f16* __restrict__ out) {
    int n = blockIdx.z, c0 = blockIdx.y * 32, s0 = blockIdx.x * 64;
    __shared__ float tile[32][65];
    int tx = threadIdx.x & 63, ty = threadIdx.x >> 6;
    const float* Xb = X + ((size_t)n * CN + c0) * SN + s0;
    #pragma unroll
    for (int cy = ty; cy < 32; cy += 4)
        tile[cy][tx] = Xb[(size_t)cy * SN + tx] - meanT[c0 + cy];
    __syncthreads();
    int cc = threadIdx.x & 31, sy = threadIdx.x >> 5;
    f16* ob = out + ((size_t)n * SN + s0) * CN + c0;
    #pragma unroll
    for (int sr = sy; sr < 64; sr += 8)
        ob[(size_t)sr * CN + cc] = (f16)tile[cc][sr];
}

__global__ __launch_bounds__(256) void k_nrm(f16* __restrict__ Ah,
                                             f16* __restrict__ Bh) {
    int w = threadIdx.x >> 6, lane = threadIdx.x & 63;
    int idx = blockIdx.x * 4 + w;
    f16x4* pa = (f16x4*)(Ah + (size_t)idx * CN + lane * 4);
    f16x4* pb = (f16x4*)(Bh + (size_t)idx * CN + lane * 4);
    f16x4 a = *pa, b = *pb;
    float sa = 0.f, sb = 0.f;
    #pragma unroll
    for (int j = 0; j < 4; ++j) {
        float x = (float)a[j]; sa += x * x;
        float y = (float)b[j]; sb += y * y;
    }
    #pragma unroll
    for (int d = 1; d < 64; d <<= 1) {
        sa += __shfl_xor(sa, d, 64);
        sb += __shfl_xor(sb, d, 64);
    }
    float ra = rsqrtf(sa), rb = rsqrtf(sb);
    #pragma unroll
    for (int j = 0; j < 4; ++j) {
        a[j] = (f16)((float)a[j] * ra);
        b[j] = (f16)((float)b[j] * rb);
    }
    *pa = a; *pb = b;
}

// ---------------- pass 0: GEMM (R3 structure) + cache S ----------------
// R3's proven 2-barrier counted-vmcnt skeleton (68.6 us, 124 VGPR, no
// spill), pass-0 semantics only, plus: per-tile epilogue rounds acc to f16
// and stores it to S[n][j][i] (8-B f16x4: 4 consecutive i per thread), and
// the per-row max is taken over the ROUNDED values (cross-pass consistency
// with the streaming passes that read S). vmcnt ledger: ks3's wait becomes
// vmcnt(20) (16 stores + 4 next-DMA younger than the drained stage DMA).
__global__ __launch_bounds__(512, 1) void k_gemm_s(const f16* __restrict__ A,
                                                   const f16* __restrict__ B,
                                                   float* __restrict__ outP,
                                                   f16* __restrict__ Sws) {
    const int n = blockIdx.z, chunk = blockIdx.y, ft = blockIdx.x;
    const int tid = threadIdx.x, lane = tid & 63, wv = tid >> 6;
    const int wr = wv >> 1, wc = wv & 1, quad = lane >> 4, lrow = lane & 15;
    // NOTE: R3 wave layout: 8 waves as 2 (wr, rows) x 4 (wc, cols)
    const int wr4 = wv >> 2, wc4 = wv & 3;

    __shared__ f16 Abuf[4][128 * 64];   // 64 KB persistent A tile (h-major)
    __shared__ f16 Bb[2][256 * 64];     // 2 x 32 KB double-buffered B stage

    const f16* At = A + ((size_t)n * SN + (size_t)ft * 128) * CN;
    const f16* Bc = B + ((size_t)n * SN + (size_t)chunk * (TPC * 256)) * CN;
    f16* Sn = Sws + (size_t)n * SN * SN;
    const int ibase_th = ft * 128 + wr4 * 64 + quad * 4;

    // ---- prologue: A tile (8 gld16/thread), then B stages 0 and 1 ----
    #pragma unroll
    for (int h = 0; h < 4; ++h) {
        #pragma unroll
        for (int it = 0; it < 2; ++it) {
            int q = it * 512 + tid;
            int row = q >> 3, c = q & 7;
            int cg = c ^ (row & 7);
            gld16(At + (size_t)row * CN + h * 64 + cg * 8,
                  Abuf[h] + (q & ~63) * 8);
        }
    }
    stageB(Bc, Bb[0], tid);         // stage 0
    stageB(Bc + 64, Bb[1], tid);    // stage 1

    int offA[4][2], offB[4][2];
    #pragma unroll
    for (int i = 0; i < 4; ++i) {
        int ra = wr4 * 64 + i * 16 + lrow;
        int rb = wc4 * 64 + i * 16 + lrow;
        #pragma unroll
        for (int kk = 0; kk < 2; ++kk) {
            offA[i][kk] = ra * 64 + (((kk * 4 + quad) ^ (ra & 7)) * 8);
            offB[i][kk] = rb * 64 + (((kk * 4 + quad) ^ (rb & 7)) * 8);
        }
    }

    float runRow[4][4];
    #pragma unroll
    for (int mt = 0; mt < 4; ++mt)
        #pragma unroll
        for (int v = 0; v < 4; ++v) runRow[mt][v] = -3.0e38f;

    // outstanding: A(8) + S0(4) + S1(4); vmcnt(4) leaves only S1
    asm volatile("s_waitcnt vmcnt(4)" ::: "memory");
    __builtin_amdgcn_s_barrier();

#define BAR()    __builtin_amdgcn_s_barrier()
#define WAIT4()  asm volatile("s_waitcnt vmcnt(4)" ::: "memory")
#define WAIT20() asm volatile("s_waitcnt vmcnt(20)" ::: "memory")
#define WAIT0()  asm volatile("s_waitcnt vmcnt(0)" ::: "memory")

#define STAGE(h, bi)                                                      \
    { _Pragma("unroll")                                                   \
      for (int kk = 0; kk < 2; ++kk) {                                    \
          f16x8 af[4], bf[4];                                             \
          _Pragma("unroll")                                               \
          for (int mt = 0; mt < 4; ++mt)                                  \
              af[mt] = *(const f16x8*)&Abuf[h][offA[mt][kk]];             \
          _Pragma("unroll")                                               \
          for (int nt = 0; nt < 4; ++nt)                                  \
              bf[nt] = *(const f16x8*)&Bb[bi][offB[nt][kk]];              \
          _Pragma("unroll")                                               \
          for (int mt = 0; mt < 4; ++mt)                                  \
              _Pragma("unroll")                                           \
              for (int nt = 0; nt < 4; ++nt)                              \
                  acc[mt][nt] = __builtin_amdgcn_mfma_f32_16x16x32_f16(   \
                      af[mt], bf[nt], acc[mt][nt], 0, 0, 0);              \
      } }

// round to f16, store S[j][i] (8-B per (mt,nt)), max over rounded values
#define EPILOGUE_S(T)                                                     \
    { int jb = (chunk * TPC + (T)) * 256;                                 \
      f16* Sth = Sn + (size_t)(jb + wc4 * 64 + lrow) * SN + ibase_th;     \
      _Pragma("unroll")                                                   \
      for (int mt = 0; mt < 4; ++mt)                                      \
          _Pragma("unroll")                                               \
          for (int nt = 0; nt < 4; ++nt) {                                \
              f16x4 hq;                                                   \
              _Pragma("unroll")                                           \
              for (int v = 0; v < 4; ++v) hq[v] = (f16)acc[mt][nt][v];    \
              *(f16x4*)(Sth + (size_t)nt * 16 * SN + mt * 16) = hq;       \
              _Pragma("unroll")                                           \
              for (int v = 0; v < 4; ++v)                                 \
                  runRow[mt][v] = fmaxf(runRow[mt][v], (float)hq[v]);     \
          } }

    f32x4 acc[4][4];

    #pragma unroll 1
    for (int t = 0; t < TPC - 1; ++t) {
        const f16* Bt = Bc + (size_t)t * (256 * CN);

        #pragma unroll
        for (int mt = 0; mt < 4; ++mt)
            #pragma unroll
            for (int nt = 0; nt < 4; ++nt) acc[mt][nt] = (f32x4){0.f, 0.f, 0.f, 0.f};

        STAGE(0, 0) BAR(); stageB(Bt + 128, Bb[0], tid);            WAIT4(); BAR();
        STAGE(1, 1) BAR(); stageB(Bt + 192, Bb[1], tid);            WAIT4(); BAR();
        STAGE(2, 0) BAR(); stageB(Bt + 256 * CN, Bb[0], tid);       WAIT4(); BAR();
        STAGE(3, 1) BAR(); stageB(Bt + 256 * CN + 64, Bb[1], tid);
        EPILOGUE_S(t);                                              WAIT20(); BAR();
    }

    // ---- peeled last tile ----
    {
        const int t = TPC - 1;
        const f16* Bt = Bc + (size_t)t * (256 * CN);

        #pragma unroll
        for (int mt = 0; mt < 4; ++mt)
            #pragma unroll
            for (int nt = 0; nt < 4; ++nt) acc[mt][nt] = (f32x4){0.f, 0.f, 0.f, 0.f};

        STAGE(0, 0) BAR(); stageB(Bt + 128, Bb[0], tid); WAIT4(); BAR();
        STAGE(1, 1) BAR(); stageB(Bt + 192, Bb[1], tid); WAIT4(); BAR();
        STAGE(2, 0) WAIT0(); BAR();
        STAGE(3, 1)
        EPILOGUE_S(t);        // trailing stores drain at wave end
    }
#undef STAGE
#undef EPILOGUE_S
#undef BAR
#undef WAIT4
#undef WAIT20
#undef WAIT0

    // ---- rowmax reduction (R3 tail, red aliased onto Bb) ----
    __syncthreads();
    float* red = (float*)&Bb[0][0];
    #pragma unroll
    for (int mt = 0; mt < 4; ++mt)
        #pragma unroll
        for (int v = 0; v < 4; ++v) {
            float val = runRow[mt][v];
            #pragma unroll
            for (int d = 1; d < 16; d <<= 1)
                val = fmaxf(val, __shfl_xor(val, d, 64));
            if (lrow == 0) red[wc4 * 128 + wr4 * 64 + mt * 16 + quad * 4 + v] = val;
        }
    __syncthreads();
    if (tid < 128) {
        float a = red[tid], b = red[128 + tid];
        float c = red[256 + tid], d = red[384 + tid];
        outP[(size_t)(n * NCHUNK + chunk) * SN + ft * 128 + tid] =
            fmaxf(fmaxf(a, b), fmaxf(c, d));
    }
}

// ---------------- fallback 3-pass GEMM (R3 verbatim) ----------------
template <int PASS>
__global__ __launch_bounds__(512, 2) void k_gemm3(const f16* __restrict__ A,
                                                  const f16* __restrict__ B,
                                                  const float* __restrict__ grow,
                                                  const float* __restrict__ alpha,
                                                  float* __restrict__ outP) {
    const int n = blockIdx.z, chunk = blockIdx.y, ft = blockIdx.x;
    const int tid = threadIdx.x, lane = tid & 63, wv = tid >> 6;
    const int wr = wv >> 2, wc = wv & 3, quad = lane >> 4, lrow = lane & 15;

    __shared__ f16 Abuf[4][128 * 64];
    __shared__ f16 Bb[2][256 * 64];

    const f16* At = A + ((size_t)n * SN + (size_t)ft * 128) * CN;
    const f16* Bc = B + ((size_t)n * SN + (size_t)chunk * (TPC * 256)) * CN;

    const float L2E = 1.44269504089f;
    const float TENL2E = 14.4269504089f;
    float a1c[4][4];
    if constexpr (PASS == 1) {
        #pragma unroll
        for (int mt = 0; mt < 4; ++mt)
            #pragma unroll
            for (int v = 0; v < 4; ++v) {
                int r = ft * 128 + wr * 64 + mt * 16 + quad * 4 + v;
                a1c[mt][v] = 0.5f * grow[(size_t)n * SN + r] * L2E;
            }
    }

    #pragma unroll
    for (int h = 0; h < 4; ++h) {
        #pragma unroll
        for (int it = 0; it < 2; ++it) {
            int q = it * 512 + tid;
            int row = q >> 3, c = q & 7;
            int cg = c ^ (row & 7);
            gld16(At + (size_t)row * CN + h * 64 + cg * 8,
                  Abuf[h] + (q & ~63) * 8);
        }
    }
    stageB(Bc, Bb[0], tid);
    stageB(Bc + 64, Bb[1], tid);

    int offA[4][2], offB[4][2];
    #pragma unroll
    for (int i = 0; i < 4; ++i) {
        int ra = wr * 64 + i * 16 + lrow;
        int rb = wc * 64 + i * 16 + lrow;
        #pragma unroll
        for (int kk = 0; kk < 2; ++kk) {
            offA[i][kk] = ra * 64 + (((kk * 4 + quad) ^ (ra & 7)) * 8);
            offB[i][kk] = rb * 64 + (((kk * 4 + quad) ^ (rb & 7)) * 8);
        }
    }

    float runRow[4][4];
    #pragma unroll
    for (int mt = 0; mt < 4; ++mt)
        #pragma unroll
        for (int v = 0; v < 4; ++v) runRow[mt][v] = (PASS == 1) ? 0.f : -3.0e38f;

    float gl[4], al[4];

    asm volatile("s_waitcnt vmcnt(4)" ::: "memory");
    __builtin_amdgcn_s_barrier();

#define BAR() __builtin_amdgcn_s_barrier()
#define WAIT4() asm volatile("s_waitcnt vmcnt(4)" ::: "memory")
#define WAIT0() asm volatile("s_waitcnt vmcnt(0)" ::: "memory")

#define STAGE(h, bi)                                                      \
    { _Pragma("unroll")                                                   \
      for (int kk = 0; kk < 2; ++kk) {                                    \
          f16x8 af[4], bf[4];                                             \
          _Pragma("unroll")                                               \
          for (int mt = 0; mt < 4; ++mt)                                  \
              af[mt] = *(const f16x8*)&Abuf[h][offA[mt][kk]];             \
          _Pragma("unroll")                                               \
          for (int nt = 0; nt < 4; ++nt)                                  \
              bf[nt] = *(const f16x8*)&Bb[bi][offB[nt][kk]];              \
          _Pragma("unroll")                                               \
          for (int mt = 0; mt < 4; ++mt)                                  \
              _Pragma("unroll")                                           \
              for (int nt = 0; nt < 4; ++nt)                              \
                  acc[mt][nt] = __builtin_amdgcn_mfma_f32_16x16x32_f16(   \
                      af[mt], bf[nt], acc[mt][nt], 0, 0, 0);              \
      } }

#define EPILOGUE()                                                        \
    if constexpr (PASS == 0) {                                            \
        _Pragma("unroll")                                                 \
        for (int mt = 0; mt < 4; ++mt)                                    \
            _Pragma("unroll")                                             \
            for (int v = 0; v < 4; ++v) {                                 \
                float m = fmaxf(fmaxf(acc[mt][0][v], acc[mt][1][v]),      \
                                fmaxf(acc[mt][2][v], acc[mt][3][v]));     \
                runRow[mt][v] = fmaxf(runRow[mt][v], m);                  \
            }                                                             \
    } else if constexpr (PASS == 1) {                                     \
        _Pragma("unroll")                                                 \
        for (int mt = 0; mt < 4; ++mt)                                    \
            _Pragma("unroll")                                             \
            for (int v = 0; v < 4; ++v) {                                 \
                float a1 = a1c[mt][v], a0 = TENL2E - a1;                  \
                float s2 = runRow[mt][v];                                 \
                _Pragma("unroll")                                         \
                for (int nt = 0; nt < 4; ++nt) {                          \
                    float arg = fminf(TENL2E,                             \
                                      fmaf(acc[mt][nt][v], a1, a0));      \
                    s2 += exp2f(arg);                                     \
                }                                                         \
                runRow[mt][v] = s2;                                       \
            }                                                             \
    } else {                                                              \
        _Pragma("unroll")                                                 \
        for (int mt = 0; mt < 4; ++mt)                                    \
            _Pragma("unroll")                                             \
            for (int v = 0; v < 4; ++v) {                                 \
                _Pragma("unroll")                                         \
                for (int nt = 0; nt < 4; ++nt) {                          \
                    float raw = fmaxf(0.f, fmaf(acc[mt][nt][v], -0.5f, 0.5f)); \
                    float lc = fmaf(-gl[nt], raw, al[nt]);                \
                    runRow[mt][v] = fmaxf(runRow[mt][v], lc);             \
                }                                                         \
            }                                                             \
    }

    f32x4 acc[4][4];

    #pragma unroll 1
    for (int t = 0; t < TPC - 1; ++t) {
        const f16* Bt = Bc + (size_t)t * (256 * CN);

        if constexpr (PASS == 2) {
            #pragma unroll
            for (int nt = 0; nt < 4; ++nt) {
                int i = (chunk * TPC + t) * 256 + wc * 64 + nt * 16 + lrow;
                gl[nt] = grow[(size_t)n * SN + i];
                al[nt] = alpha[(size_t)n * SN + i];
            }
        }

        #pragma unroll
        for (int mt = 0; mt < 4; ++mt)
            #pragma unroll
            for (int nt = 0; nt < 4; ++nt) acc[mt][nt] = (f32x4){0.f, 0.f, 0.f, 0.f};

        STAGE(0, 0) BAR(); stageB(Bt + 128, Bb[0], tid);            WAIT4(); BAR();
        STAGE(1, 1) BAR(); stageB(Bt + 192, Bb[1], tid);            WAIT4(); BAR();
        STAGE(2, 0) BAR(); stageB(Bt + 256 * CN, Bb[0], tid);       WAIT4(); BAR();
        STAGE(3, 1) BAR(); stageB(Bt + 256 * CN + 64, Bb[1], tid);
        EPILOGUE();                                                 WAIT4(); BAR();
    }

    {
        const int t = TPC - 1;
        const f16* Bt = Bc + (size_t)t * (256 * CN);

        if constexpr (PASS == 2) {
            #pragma unroll
            for (int nt = 0; nt < 4; ++nt) {
                int i = (chunk * TPC + t) * 256 + wc * 64 + nt * 16 + lrow;
                gl[nt] = grow[(size_t)n * SN + i];
                al[nt] = alpha[(size_t)n * SN + i];
            }
        }

        #pragma unroll
        for (int mt = 0; mt < 4; ++mt)
            #pragma unroll
            for (int nt = 0; nt < 4; ++nt) acc[mt][nt] = (f32x4){0.f, 0.f, 0.f, 0.f};

        STAGE(0, 0) BAR(); stageB(Bt + 128, Bb[0], tid); WAIT4(); BAR();
        STAGE(1, 1) BAR(); stageB(Bt + 192, Bb[1], tid); WAIT4(); BAR();
        STAGE(2, 0) WAIT0(); BAR();
        STAGE(3, 1)
        EPILOGUE();
    }
#undef STAGE
#undef EPILOGUE
#undef BAR
#undef WAIT4
#undef WAIT0

    __syncthreads();
    float* red = (float*)&Bb[0][0];
    #pragma unroll
    for (int mt = 0; mt < 4; ++mt)
        #pragma unroll
        for (int v = 0; v < 4; ++v) {
            float val = runRow[mt][v];
            #pragma unroll
            for (int d = 1; d < 16; d <<= 1) {
                float o = __shfl_xor(val, d, 64);
                val = (PASS == 1) ? (val + o) : fmaxf(val, o);
            }
            if (lrow == 0) red[wc * 128 + wr * 64 + mt * 16 + quad * 4 + v] = val;
        }
    __syncthreads();
    if (tid < 128) {
        float a = red[tid], b = red[128 + tid];
        float c = red[256 + tid], d = red[384 + tid];
        float r = (PASS == 1) ? (a + b + c + d)
                              : fmaxf(fmaxf(a, b), fmaxf(c, d));
        outP[(size_t)(n * NCHUNK + chunk) * SN + ft * 128 + tid] = r;
    }
}

// ---------------- streaming pass 1: per-i sum of exp over j ----------------
// grid (x=NJC, y=NIP, z=n), 256 thr. Thread's i-octet FIXED -> coefficients
// live in 16 regs. Reads S[j][i0..i0+8) as f16x8: 32-lane groups cover 512 B
// contiguous. Per-block partial sums over 400 j's -> sumP[n][jc][i].
__global__ __launch_bounds__(256) void k_rowsum(const f16* __restrict__ S,
                                                const float* __restrict__ grow,
                                                float* __restrict__ sumP) {
    const int n = blockIdx.z, ip = blockIdx.y, jc = blockIdx.x;
    const int t = threadIdx.x;
    const int i0 = ip * 256 + (t & 31) * 8;
    const int jb = jc * 400;
    const f16* Sn = S + (size_t)n * SN * SN;
    const float L2E = 1.44269504089f;
    const float TENL2E = 14.4269504089f;

    f32x4 g0 = *(const f32x4*)&grow[(size_t)n * SN + i0];
    f32x4 g1 = *(const f32x4*)&grow[(size_t)n * SN + i0 + 4];
    float c1[8], a0[8];
    #pragma unroll
    for (int k = 0; k < 4; ++k) {
        c1[k] = 0.5f * g0[k] * L2E;     a0[k] = TENL2E - c1[k];
        c1[4 + k] = 0.5f * g1[k] * L2E; a0[4 + k] = TENL2E - c1[4 + k];
    }

    float s8[8];
    #pragma unroll
    for (int k = 0; k < 8; ++k) s8[k] = 0.f;

    #pragma unroll 2
    for (int jt = 0; jt < 50; ++jt) {
        int j = jb + jt * 8 + (t >> 5);
        f16x8 v = *(const f16x8*)(Sn + (size_t)j * SN + i0);
        #pragma unroll
        for (int k = 0; k < 8; ++k) {
            float arg = fminf(TENL2E, fmaf((float)v[k], c1[k], a0[k]));
            s8[k] += exp2f(arg);
        }
    }

    __shared__ float red[8][256];
    #pragma unroll
    for (int k = 0; k < 8; ++k) red[t >> 5][(t & 31) * 8 + k] = s8[k];
    __syncthreads();
    float s = 0.f;
    #pragma unroll
    for (int r = 0; r < 8; ++r) s += red[r][t];
    sumP[((size_t)n * NJC + jc) * SN + ip * 256 + t] = s;
}

// ---------------- streaming pass 2: per-j max over i ----------------
// grid (x=NJC, y=NIP, z=n): block = i-panel ip (256 i) x j-chunk jc (400 j).
// Per j: 32-lane shuffle-max over the 256-i panel -> colmaxP[n][ip][j].
__global__ __launch_bounds__(256) void k_colmax(const f16* __restrict__ S,
                                                const float* __restrict__ grow,
                                                const float* __restrict__ alpha,
                                                float* __restrict__ colmaxP) {
    const int n = blockIdx.z, ip = blockIdx.y, jc = blockIdx.x;
    const int t = threadIdx.x;
    const int i0 = ip * 256 + (t & 31) * 8;
    const int jb = jc * 400;
    const f16* Sn = S + (size_t)n * SN * SN;

    f32x4 g0 = *(const f32x4*)&grow[(size_t)n * SN + i0];
    f32x4 g1 = *(const f32x4*)&grow[(size_t)n * SN + i0 + 4];
    f32x4 a0 = *(const f32x4*)&alpha[(size_t)n * SN + i0];
    f32x4 a1 = *(const f32x4*)&alpha[(size_t)n * SN + i0 + 4];
    float gk[8], ak[8];
    #pragma unroll
    for (int k = 0; k < 4; ++k) {
        gk[k] = g0[k]; ak[k] = a0[k];
        gk[4 + k] = g1[k]; ak[4 + k] = a1[k];
    }

    float* outRow = colmaxP + ((size_t)n * NIP + ip) * SN;

    #pragma unroll 2
    for (int jt = 0; jt < 50; ++jt) {
        int j = jb + jt * 8 + (t >> 5);
        f16x8 v = *(const f16x8*)(Sn + (size_t)j * SN + i0);
        float m = -3.0e38f;
        #pragma unroll
        for (int k = 0; k < 8; ++k) {
            float raw = fmaxf(0.f, fmaf((float)v[k], -0.5f, 0.5f));
            m = fmaxf(m, fmaf(-gk[k], raw, ak[k]));
        }
        #pragma unroll
        for (int d = 1; d < 32; d <<= 1)
            m = fmaxf(m, __shfl_xor(m, d, 64));
        if ((t & 31) == 0) outRow[j] = m;
    }
}

// ---------------- small reduce kernels ----------------

__global__ __launch_bounds__(256) void r_g(const float* __restrict__ rowmaxP,
                                           float* __restrict__ grow) {
    int idx = blockIdx.x * 256 + threadIdx.x;
    int n = idx / SN, i = idx - n * SN;
    float m = -3.0e38f;
    for (int ch = 0; ch < NCHUNK; ++ch)
        m = fmaxf(m, rowmaxP[(size_t)(n * NCHUNK + ch) * SN + i]);
    float mr = fmaxf(0.f, (1.f - m) * 0.5f);
    grow[idx] = 10.f / (mr + 1e-5f);
}

__global__ __launch_bounds__(256) void r_alpha(const float* __restrict__ rowsumP,
                                               float* __restrict__ alpha, int nch) {
    int idx = blockIdx.x * 256 + threadIdx.x;
    int n = idx / SN, i = idx - n * SN;
    float s = 0.f;
    for (int ch = 0; ch < nch; ++ch)
        s += rowsumP[(size_t)(n * nch + ch) * SN + i];
    alpha[idx] = 10.f - logf(s);
}

__global__ __launch_bounds__(256) void r_colfin(const float* __restrict__ colmaxP,
                                                float* __restrict__ bsum, int nch) {
    int idx = blockIdx.x * 256 + threadIdx.x;
    int n = idx / SN, j = idx - n * SN;
    float m = -3.0e38f;
    for (int ch = 0; ch < nch; ++ch)
        m = fmaxf(m, colmaxP[(size_t)(n * nch + ch) * SN + j]);
    float v = expf(m);
    #pragma unroll
    for (int d = 1; d < 64; d <<= 1) v += __shfl_xor(v, d, 64);
    __shared__ float sb[4];
    if ((threadIdx.x & 63) == 0) sb[threadIdx.x >> 6] = v;
    __syncthreads();
    if (threadIdx.x == 0) bsum[blockIdx.x] = sb[0] + sb[1] + sb[2] + sb[3];
}

__global__ __launch_bounds__(64) void r_loss(const float* __restrict__ bsum,
                                             float* __restrict__ out) {
    int t = threadIdx.x;
    float v = (t < 50) ? bsum[t] : 0.f;
    float v0 = (t < 25) ? v : 0.f;
    float v1 = (t >= 25 && t < 50) ? v : 0.f;
    #pragma unroll
    for (int d = 1; d < 64; d <<= 1) {
        v0 += __shfl_xor(v0, d, 64);
        v1 += __shfl_xor(v1, d, 64);
    }
    if (t == 0) {
        float cs0 = v0 * (1.0f / SN), cs1 = v1 * (1.0f / SN);
        out[0] = -0.5f * (logf(cs0) + logf(cs1));
    }
}

// ---------------- launch ----------------

extern "C" void kernel_launch(void* const* d_in, const int* in_sizes, int n_in,
                              void* d_out, int out_size, void* d_ws, size_t ws_size,
                              hipStream_t stream) {
    const float* I = (const float*)d_in[0];
    const float* T = (const float*)d_in[1];
    float* out = (float*)d_out;

    float* wsf = (float*)d_ws;
    float* meanT = wsf;                         // 256
    float* grow  = meanT + 256;                 // 12800
    float* alpha = grow + 12800;                // 12800
    float* rowmaxP = alpha + 12800;             // 64000 (5 chunks)
    float* sumP  = rowmaxP + 64000;             // 204800 (16 chunks; fallback uses 5)
    float* colmaxP = sumP + 204800;             // 320000 (25 panels; fallback uses 5)
    float* bsum = colmaxP + 320000;             // 64
    f16* Ah = (f16*)(bsum + 64);                // 2*6400*256 f16
    f16* Bh = Ah + (size_t)NBATCH * SN * CN;
    f16* Sws = Bh + (size_t)NBATCH * SN * CN;   // 2*6400*6400 f16 = 163.84 MB

    const size_t NEEDED = (size_t)614720 * 4
                        + (size_t)2 * NBATCH * SN * CN * 2
                        + (size_t)NBATCH * SN * SN * 2;
    const bool cached = ws_size >= NEEDED;

    k_meanT<<<256, 256, 0, stream>>>(T, meanT);
    k_xpose<<<dim3(100, 8, 2), 256, 0, stream>>>(I, meanT, Ah);
    k_xpose<<<dim3(100, 8, 2), 256, 0, stream>>>(T, meanT, Bh);
    k_nrm<<<3200, 256, 0, stream>>>(Ah, Bh);

    dim3 gg(NTILES, NCHUNK, NBATCH);
    if (cached) {
        k_gemm_s<<<gg, 512, 0, stream>>>(Ah, Bh, rowmaxP, Sws);
        r_g<<<50, 256, 0, stream>>>(rowmaxP, grow);
        k_rowsum<<<dim3(NJC, NIP, NBATCH), 256, 0, stream>>>(Sws, grow, sumP);
        r_alpha<<<50, 256, 0, stream>>>(sumP, alpha, NJC);
        k_colmax<<<dim3(NJC, NIP, NBATCH), 256, 0, stream>>>(Sws, grow, alpha, colmaxP);
        r_colfin<<<50, 256, 0, stream>>>(colmaxP, bsum, NIP);
    } else {
        k_gemm3<0><<<gg, 512, 0, stream>>>(Ah, Bh, nullptr, nullptr, rowmaxP);
        r_g<<<50, 256, 0, stream>>>(rowmaxP, grow);
        k_gemm3<1><<<gg, 512, 0, stream>>>(Ah, Bh, grow, nullptr, sumP);
        r_alpha<<<50, 256, 0, stream>>>(sumP, alpha, NCHUNK);
        k_gemm3<2><<<gg, 512, 0, stream>>>(Bh, Ah, grow, alpha, colmaxP);
        r_colfin<<<50, 256, 0, stream>>>(colmaxP, bsum, NCHUNK);
    }
    r_loss<<<1, 64, 0, stream>>>(bsum, out);
}

// Round 11
// 241.296 us; speedup vs baseline: 1.6895x; 1.0349x over previous
//
#include <hip/hip_runtime.h>

#define SN 6400      // H*W
#define CN 256       // channels (= GEMM K)
#define NBATCH 2
#define NTILES 50    // SN / 128 (fixed-side row tiles, GEMM)
#define NCHUNK 5     // streamed-side chunks (GEMM grid = 50*5*2 = 500 blocks)
#define TPC 5        // 256-wide streamed tiles per chunk
#define NJC 25       // streaming j-chunks (6400/256)
#define NIP 25       // i/j panels of 256

typedef _Float16 f16;
typedef f16 f16x8 __attribute__((ext_vector_type(8)));
typedef f16 f16x4 __attribute__((ext_vector_type(4)));
typedef float f32x4 __attribute__((ext_vector_type(4)));

__device__ __forceinline__ void gld16(const f16* g, f16* l) {
    __builtin_amdgcn_global_load_lds(
        (__attribute__((address_space(1))) void*)(g),
        (__attribute__((address_space(3))) void*)(l), 16, 0, 0);
}

// Stage a 256-row x 64-half (32 KB) K-chunk into LDS with 512 threads
// (4 gld16/thread). XOR source swizzle; verified conflict-free (R0-R10).
__device__ __forceinline__ void stageB(const f16* __restrict__ g,
                                       f16* l, int tid) {
    #pragma unroll
    for (int it = 0; it < 4; ++it) {
        int q = it * 512 + tid;
        int row = q >> 3, c = q & 7;
        int cg = c ^ (row & 7);
        gld16(g + (size_t)row * CN + cg * 8, l + (q & ~63) * 8);
    }
}

// ---------------- prep kernels (unchanged) ----------------

__global__ __launch_bounds__(256) void k_meanT(const float* __restrict__ T,
                                               float* __restrict__ meanT) {
    int c = blockIdx.x, t = threadIdx.x;
    const float* p0 = T + (size_t)c * SN;
    const float* p1 = T + (size_t)(CN + c) * SN;
    float s = 0.f;
    for (int i = t; i < SN; i += 256) s += p0[i] + p1[i];
    #pragma unroll
    for (int d = 1; d < 64; d <<= 1) s += __shfl_xor(s, d, 64);
    __shared__ float sb[4];
    if ((t & 63) == 0) sb[t >> 6] = s;
    __syncthreads();
    if (t == 0) meanT[c] = (sb[0] + sb[1] + sb[2] + sb[3]) * (1.0f / 12800.0f);
}

__global__ __launch_bounds__(256) void k_xpose(const float* __restrict__ X,
                                               const float* __restrict__ meanT,
                                               f16* __restrict__ out) {
    int n = blockIdx.z, c0 = blockIdx.y * 32, s0 = blockIdx.x * 64;
    __shared__ float tile[32][65];
    int tx = threadIdx.x & 63, ty = threadIdx.x >> 6;
    const float* Xb = X + ((size_t)n * CN + c0) * SN + s0;
    #pragma unroll
    for (int cy = ty; cy < 32; cy += 4)
        tile[cy][tx] = Xb[(size_t)cy * SN + tx] - meanT[c0 + cy];
    __syncthreads();
    int cc = threadIdx.x & 31, sy = threadIdx.x >> 5;
    f16* ob = out + ((size_t)n * SN + s0) * CN + c0;
    #pragma unroll
    for (int sr = sy; sr < 64; sr += 8)
        ob[(size_t)sr * CN + cc] = (f16)tile[cc][sr];
}

__global__ __launch_bounds__(256) void k_nrm(f16* __restrict__ Ah,
                                             f16* __restrict__ Bh) {
    int w = threadIdx.x >> 6, lane = threadIdx.x & 63;
    int idx = blockIdx.x * 4 + w;
    f16x4* pa = (f16x4*)(Ah + (size_t)idx * CN + lane * 4);
    f16x4* pb = (f16x4*)(Bh + (size_t)idx * CN + lane * 4);
    f16x4 a = *pa, b = *pb;
    float sa = 0.f, sb = 0.f;
    #pragma unroll
    for (int j = 0; j < 4; ++j) {
        float x = (float)a[j]; sa += x * x;
        float y = (float)b[j]; sb += y * y;
    }
    #pragma unroll
    for (int d = 1; d < 64; d <<= 1) {
        sa += __shfl_xor(sa, d, 64);
        sb += __shfl_xor(sb, d, 64);
    }
    float ra = rsqrtf(sa), rb = rsqrtf(sb);
    #pragma unroll
    for (int j = 0; j < 4; ++j) {
        a[j] = (f16)((float)a[j] * ra);
        b[j] = (f16)((float)b[j] * rb);
    }
    *pa = a; *pb = b;
}

// ---------------- pass 0: GEMM (R3 structure) + cache S ----------------
// R10 + store-drain fix: per-wave VMEM order at ks3 is [D(ks3), stores(16),
// D(ks0)]. R10's ks0-end WAIT4 kept only the newest 4 -> force-drained all
// 16 S-stores ONE stage after issue. Now ks0-end is WAIT20 for t>=1 (leaves
// stores + D(ks0) in flight; drains D(prev ks3) which ks1 reads). Stores get
// two stages of slack before the unavoidable drain at ks1-end's WAIT4.
// t==0 ks0-end stays WAIT4 (must drain the prologue's S1 DMA; no stores yet).
__global__ __launch_bounds__(512, 1) void k_gemm_s(const f16* __restrict__ A,
                                                   const f16* __restrict__ B,
                                                   float* __restrict__ outP,
                                                   f16* __restrict__ Sws) {
    const int n = blockIdx.z, chunk = blockIdx.y, ft = blockIdx.x;
    const int tid = threadIdx.x, lane = tid & 63, wv = tid >> 6;
    const int quad = lane >> 4, lrow = lane & 15;
    const int wr4 = wv >> 2, wc4 = wv & 3;

    __shared__ f16 Abuf[4][128 * 64];   // 64 KB persistent A tile (h-major)
    __shared__ f16 Bb[2][256 * 64];     // 2 x 32 KB double-buffered B stage

    const f16* At = A + ((size_t)n * SN + (size_t)ft * 128) * CN;
    const f16* Bc = B + ((size_t)n * SN + (size_t)chunk * (TPC * 256)) * CN;
    f16* Sn = Sws + (size_t)n * SN * SN;
    const int ibase_th = ft * 128 + wr4 * 64 + quad * 4;

    // ---- prologue: A tile (8 gld16/thread), then B stages 0 and 1 ----
    #pragma unroll
    for (int h = 0; h < 4; ++h) {
        #pragma unroll
        for (int it = 0; it < 2; ++it) {
            int q = it * 512 + tid;
            int row = q >> 3, c = q & 7;
            int cg = c ^ (row & 7);
            gld16(At + (size_t)row * CN + h * 64 + cg * 8,
                  Abuf[h] + (q & ~63) * 8);
        }
    }
    stageB(Bc, Bb[0], tid);         // stage 0
    stageB(Bc + 64, Bb[1], tid);    // stage 1

    int offA[4][2], offB[4][2];
    #pragma unroll
    for (int i = 0; i < 4; ++i) {
        int ra = wr4 * 64 + i * 16 + lrow;
        int rb = wc4 * 64 + i * 16 + lrow;
        #pragma unroll
        for (int kk = 0; kk < 2; ++kk) {
            offA[i][kk] = ra * 64 + (((kk * 4 + quad) ^ (ra & 7)) * 8);
            offB[i][kk] = rb * 64 + (((kk * 4 + quad) ^ (rb & 7)) * 8);
        }
    }

    float runRow[4][4];
    #pragma unroll
    for (int mt = 0; mt < 4; ++mt)
        #pragma unroll
        for (int v = 0; v < 4; ++v) runRow[mt][v] = -3.0e38f;

    // outstanding: A(8) + S0(4) + S1(4); vmcnt(4) leaves only S1
    asm volatile("s_waitcnt vmcnt(4)" ::: "memory");
    __builtin_amdgcn_s_barrier();

#define BAR()    __builtin_amdgcn_s_barrier()
#define WAIT4()  asm volatile("s_waitcnt vmcnt(4)" ::: "memory")
#define WAIT20() asm volatile("s_waitcnt vmcnt(20)" ::: "memory")
#define WAIT0()  asm volatile("s_waitcnt vmcnt(0)" ::: "memory")

#define STAGE(h, bi)                                                      \
    { _Pragma("unroll")                                                   \
      for (int kk = 0; kk < 2; ++kk) {                                    \
          f16x8 af[4], bf[4];                                             \
          _Pragma("unroll")                                               \
          for (int mt = 0; mt < 4; ++mt)                                  \
              af[mt] = *(const f16x8*)&Abuf[h][offA[mt][kk]];             \
          _Pragma("unroll")                                               \
          for (int nt = 0; nt < 4; ++nt)                                  \
              bf[nt] = *(const f16x8*)&Bb[bi][offB[nt][kk]];              \
          _Pragma("unroll")                                               \
          for (int mt = 0; mt < 4; ++mt)                                  \
              _Pragma("unroll")                                           \
              for (int nt = 0; nt < 4; ++nt)                              \
                  acc[mt][nt] = __builtin_amdgcn_mfma_f32_16x16x32_f16(   \
                      af[mt], bf[nt], acc[mt][nt], 0, 0, 0);              \
      } }

// round to f16, store S[j][i] (8-B per (mt,nt)), max over rounded values
#define EPILOGUE_S(T)                                                     \
    { int jb = (chunk * TPC + (T)) * 256;                                 \
      f16* Sth = Sn + (size_t)(jb + wc4 * 64 + lrow) * SN + ibase_th;     \
      _Pragma("unroll")                                                   \
      for (int mt = 0; mt < 4; ++mt)                                      \
          _Pragma("unroll")                                               \
          for (int nt = 0; nt < 4; ++nt) {                                \
              f16x4 hq;                                                   \
              _Pragma("unroll")                                           \
              for (int v = 0; v < 4; ++v) hq[v] = (f16)acc[mt][nt][v];    \
              *(f16x4*)(Sth + (size_t)nt * 16 * SN + mt * 16) = hq;       \
              _Pragma("unroll")                                           \
              for (int v = 0; v < 4; ++v)                                 \
                  runRow[mt][v] = fmaxf(runRow[mt][v], (float)hq[v]);     \
          } }

    f32x4 acc[4][4];

    #pragma unroll 1
    for (int t = 0; t < TPC - 1; ++t) {
        const f16* Bt = Bc + (size_t)t * (256 * CN);

        #pragma unroll
        for (int mt = 0; mt < 4; ++mt)
            #pragma unroll
            for (int nt = 0; nt < 4; ++nt) acc[mt][nt] = (f32x4){0.f, 0.f, 0.f, 0.f};

        // ks0: for t>=1, outstanding = [D(prev ks3)(4), stores(16), D(ks0)(4)]
        // -> WAIT20 drains D(prev ks3) and LEAVES the stores in flight.
        // t==0: outstanding = [S1(4), D(ks0)(4)] -> WAIT4 drains S1.
        STAGE(0, 0) BAR(); stageB(Bt + 128, Bb[0], tid);
        if (t == 0) { WAIT4(); } else { WAIT20(); }
        BAR();
        // ks1: stores (if any) are oldest; draining D(ks0) drains them too —
        // they've had ~2 stages of overlap by now.
        STAGE(1, 1) BAR(); stageB(Bt + 192, Bb[1], tid);            WAIT4(); BAR();
        STAGE(2, 0) BAR(); stageB(Bt + 256 * CN, Bb[0], tid);       WAIT4(); BAR();
        STAGE(3, 1) BAR(); stageB(Bt + 256 * CN + 64, Bb[1], tid);
        EPILOGUE_S(t);                                              WAIT20(); BAR();
    }

    // ---- peeled last tile ----
    {
        const int t = TPC - 1;
        const f16* Bt = Bc + (size_t)t * (256 * CN);

        #pragma unroll
        for (int mt = 0; mt < 4; ++mt)
            #pragma unroll
            for (int nt = 0; nt < 4; ++nt) acc[mt][nt] = (f32x4){0.f, 0.f, 0.f, 0.f};

        STAGE(0, 0) BAR(); stageB(Bt + 128, Bb[0], tid); WAIT20(); BAR();
        STAGE(1, 1) BAR(); stageB(Bt + 192, Bb[1], tid); WAIT4();  BAR();
        STAGE(2, 0) WAIT0(); BAR();
        STAGE(3, 1)
        EPILOGUE_S(t);        // trailing stores drain at wave end
    }
#undef STAGE
#undef EPILOGUE_S
#undef BAR
#undef WAIT4
#undef WAIT20
#undef WAIT0

    // ---- rowmax reduction (red aliased onto Bb) ----
    __syncthreads();
    float* red = (float*)&Bb[0][0];
    #pragma unroll
    for (int mt = 0; mt < 4; ++mt)
        #pragma unroll
        for (int v = 0; v < 4; ++v) {
            float val = runRow[mt][v];
            #pragma unroll
            for (int d = 1; d < 16; d <<= 1)
                val = fmaxf(val, __shfl_xor(val, d, 64));
            if (lrow == 0) red[wc4 * 128 + wr4 * 64 + mt * 16 + quad * 4 + v] = val;
        }
    __syncthreads();
    if (tid < 128) {
        float a = red[tid], b = red[128 + tid];
        float c = red[256 + tid], d = red[384 + tid];
        outP[(size_t)(n * NCHUNK + chunk) * SN + ft * 128 + tid] =
            fmaxf(fmaxf(a, b), fmaxf(c, d));
    }
}

// ---------------- fallback 3-pass GEMM (R3 verbatim) ----------------
template <int PASS>
__global__ __launch_bounds__(512, 2) void k_gemm3(const f16* __restrict__ A,
                                                  const f16* __restrict__ B,
                                                  const float* __restrict__ grow,
                                                  const float* __restrict__ alpha,
                                                  float* __restrict__ outP) {
    const int n = blockIdx.z, chunk = blockIdx.y, ft = blockIdx.x;
    const int tid = threadIdx.x, lane = tid & 63, wv = tid >> 6;
    const int wr = wv >> 2, wc = wv & 3, quad = lane >> 4, lrow = lane & 15;

    __shared__ f16 Abuf[4][128 * 64];
    __shared__ f16 Bb[2][256 * 64];

    const f16* At = A + ((size_t)n * SN + (size_t)ft * 128) * CN;
    const f16* Bc = B + ((size_t)n * SN + (size_t)chunk * (TPC * 256)) * CN;

    const float L2E = 1.44269504089f;
    const float TENL2E = 14.4269504089f;
    float a1c[4][4];
    if constexpr (PASS == 1) {
        #pragma unroll
        for (int mt = 0; mt < 4; ++mt)
            #pragma unroll
            for (int v = 0; v < 4; ++v) {
                int r = ft * 128 + wr * 64 + mt * 16 + quad * 4 + v;
                a1c[mt][v] = 0.5f * grow[(size_t)n * SN + r] * L2E;
            }
    }

    #pragma unroll
    for (int h = 0; h < 4; ++h) {
        #pragma unroll
        for (int it = 0; it < 2; ++it) {
            int q = it * 512 + tid;
            int row = q >> 3, c = q & 7;
            int cg = c ^ (row & 7);
            gld16(At + (size_t)row * CN + h * 64 + cg * 8,
                  Abuf[h] + (q & ~63) * 8);
        }
    }
    stageB(Bc, Bb[0], tid);
    stageB(Bc + 64, Bb[1], tid);

    int offA[4][2], offB[4][2];
    #pragma unroll
    for (int i = 0; i < 4; ++i) {
        int ra = wr * 64 + i * 16 + lrow;
        int rb = wc * 64 + i * 16 + lrow;
        #pragma unroll
        for (int kk = 0; kk < 2; ++kk) {
            offA[i][kk] = ra * 64 + (((kk * 4 + quad) ^ (ra & 7)) * 8);
            offB[i][kk] = rb * 64 + (((kk * 4 + quad) ^ (rb & 7)) * 8);
        }
    }

    float runRow[4][4];
    #pragma unroll
    for (int mt = 0; mt < 4; ++mt)
        #pragma unroll
        for (int v = 0; v < 4; ++v) runRow[mt][v] = (PASS == 1) ? 0.f : -3.0e38f;

    float gl[4], al[4];

    asm volatile("s_waitcnt vmcnt(4)" ::: "memory");
    __builtin_amdgcn_s_barrier();

#define BAR() __builtin_amdgcn_s_barrier()
#define WAIT4() asm volatile("s_waitcnt vmcnt(4)" ::: "memory")
#define WAIT0() asm volatile("s_waitcnt vmcnt(0)" ::: "memory")

#define STAGE(h, bi)                                                      \
    { _Pragma("unroll")                                                   \
      for (int kk = 0; kk < 2; ++kk) {                                    \
          f16x8 af[4], bf[4];                                             \
          _Pragma("unroll")                                               \
          for (int mt = 0; mt < 4; ++mt)                                  \
              af[mt] = *(const f16x8*)&Abuf[h][offA[mt][kk]];             \
          _Pragma("unroll")                                               \
          for (int nt = 0; nt < 4; ++nt)                                  \
              bf[nt] = *(const f16x8*)&Bb[bi][offB[nt][kk]];              \
          _Pragma("unroll")                                               \
          for (int mt = 0; mt < 4; ++mt)                                  \
              _Pragma("unroll")                                           \
              for (int nt = 0; nt < 4; ++nt)                              \
                  acc[mt][nt] = __builtin_amdgcn_mfma_f32_16x16x32_f16(   \
                      af[mt], bf[nt], acc[mt][nt], 0, 0, 0);              \
      } }

#define EPILOGUE()                                                        \
    if constexpr (PASS == 0) {                                            \
        _Pragma("unroll")                                                 \
        for (int mt = 0; mt < 4; ++mt)                                    \
            _Pragma("unroll")                                             \
            for (int v = 0; v < 4; ++v) {                                 \
                float m = fmaxf(fmaxf(acc[mt][0][v], acc[mt][1][v]),      \
                                fmaxf(acc[mt][2][v], acc[mt][3][v]));     \
                runRow[mt][v] = fmaxf(runRow[mt][v], m);                  \
            }                                                             \
    } else if constexpr (PASS == 1) {                                     \
        _Pragma("unroll")                                                 \
        for (int mt = 0; mt < 4; ++mt)                                    \
            _Pragma("unroll")                                             \
            for (int v = 0; v < 4; ++v) {                                 \
                float a1 = a1c[mt][v], a0 = TENL2E - a1;                  \
                float s2 = runRow[mt][v];                                 \
                _Pragma("unroll")                                         \
                for (int nt = 0; nt < 4; ++nt) {                          \
                    float arg = fminf(TENL2E,                             \
                                      fmaf(acc[mt][nt][v], a1, a0));      \
                    s2 += exp2f(arg);                                     \
                }                                                         \
                runRow[mt][v] = s2;                                       \
            }                                                             \
    } else {                                                              \
        _Pragma("unroll")                                                 \
        for (int mt = 0; mt < 4; ++mt)                                    \
            _Pragma("unroll")                                             \
            for (int v = 0; v < 4; ++v) {                                 \
                _Pragma("unroll")                                         \
                for (int nt = 0; nt < 4; ++nt) {                          \
                    float raw = fmaxf(0.f, fmaf(acc[mt][nt][v], -0.5f, 0.5f)); \
                    float lc = fmaf(-gl[nt], raw, al[nt]);                \
                    runRow[mt][v] = fmaxf(runRow[mt][v], lc);             \
                }                                                         \
            }                                                             \
    }

    f32x4 acc[4][4];

    #pragma unroll 1
    for (int t = 0; t < TPC - 1; ++t) {
        const f16* Bt = Bc + (size_t)t * (256 * CN);

        if constexpr (PASS == 2) {
            #pragma unroll
            for (int nt = 0; nt < 4; ++nt) {
                int i = (chunk * TPC + t) * 256 + wc * 64 + nt * 16 + lrow;
                gl[nt] = grow[(size_t)n * SN + i];
                al[nt] = alpha[(size_t)n * SN + i];
            }
        }

        #pragma unroll
        for (int mt = 0; mt < 4; ++mt)
            #pragma unroll
            for (int nt = 0; nt < 4; ++nt) acc[mt][nt] = (f32x4){0.f, 0.f, 0.f, 0.f};

        STAGE(0, 0) BAR(); stageB(Bt + 128, Bb[0], tid);            WAIT4(); BAR();
        STAGE(1, 1) BAR(); stageB(Bt + 192, Bb[1], tid);            WAIT4(); BAR();
        STAGE(2, 0) BAR(); stageB(Bt + 256 * CN, Bb[0], tid);       WAIT4(); BAR();
        STAGE(3, 1) BAR(); stageB(Bt + 256 * CN + 64, Bb[1], tid);
        EPILOGUE();                                                 WAIT4(); BAR();
    }

    {
        const int t = TPC - 1;
        const f16* Bt = Bc + (size_t)t * (256 * CN);

        if constexpr (PASS == 2) {
            #pragma unroll
            for (int nt = 0; nt < 4; ++nt) {
                int i = (chunk * TPC + t) * 256 + wc * 64 + nt * 16 + lrow;
                gl[nt] = grow[(size_t)n * SN + i];
                al[nt] = alpha[(size_t)n * SN + i];
            }
        }

        #pragma unroll
        for (int mt = 0; mt < 4; ++mt)
            #pragma unroll
            for (int nt = 0; nt < 4; ++nt) acc[mt][nt] = (f32x4){0.f, 0.f, 0.f, 0.f};

        STAGE(0, 0) BAR(); stageB(Bt + 128, Bb[0], tid); WAIT4(); BAR();
        STAGE(1, 1) BAR(); stageB(Bt + 192, Bb[1], tid); WAIT4(); BAR();
        STAGE(2, 0) WAIT0(); BAR();
        STAGE(3, 1)
        EPILOGUE();
    }
#undef STAGE
#undef EPILOGUE
#undef BAR
#undef WAIT4
#undef WAIT0

    __syncthreads();
    float* red = (float*)&Bb[0][0];
    #pragma unroll
    for (int mt = 0; mt < 4; ++mt)
        #pragma unroll
        for (int v = 0; v < 4; ++v) {
            float val = runRow[mt][v];
            #pragma unroll
            for (int d = 1; d < 16; d <<= 1) {
                float o = __shfl_xor(val, d, 64);
                val = (PASS == 1) ? (val + o) : fmaxf(val, o);
            }
            if (lrow == 0) red[wc * 128 + wr * 64 + mt * 16 + quad * 4 + v] = val;
        }
    __syncthreads();
    if (tid < 128) {
        float a = red[tid], b = red[128 + tid];
        float c = red[256 + tid], d = red[384 + tid];
        float r = (PASS == 1) ? (a + b + c + d)
                              : fmaxf(fmaxf(a, b), fmaxf(c, d));
        outP[(size_t)(n * NCHUNK + chunk) * SN + ft * 128 + tid] = r;
    }
}

// ---------------- streaming pass 1: per-i sum of exp over j ----------------
// v2: 4-way j-batched loads for memory parallelism (R10 was latency-bound at
// ~3 TB/s with ~1 load in flight/thread). Per iter: 4 INDEPENDENT f16x8
// loads (j = jb + jt*32 + group + {0,8,16,24}) issued together, then 32
// elements processed. 8 iters cover the 256-j chunk. Coefficients per-i in
// regs (thread's i-octet fixed). grid (25 jc, 25 ip, 2 n) = 1250 blocks.
__global__ __launch_bounds__(256) void k_rowsum(const f16* __restrict__ S,
                                                const float* __restrict__ grow,
                                                float* __restrict__ sumP) {
    const int n = blockIdx.z, ip = blockIdx.y, jc = blockIdx.x;
    const int t = threadIdx.x;
    const int i0 = ip * 256 + (t & 31) * 8;
    const int jb = jc * 256 + (t >> 5);
    const f16* Sn = S + (size_t)n * SN * SN;
    const float L2E = 1.44269504089f;
    const float TENL2E = 14.4269504089f;

    f32x4 g0 = *(const f32x4*)&grow[(size_t)n * SN + i0];
    f32x4 g1 = *(const f32x4*)&grow[(size_t)n * SN + i0 + 4];
    float c1[8], a0[8];
    #pragma unroll
    for (int k = 0; k < 4; ++k) {
        c1[k] = 0.5f * g0[k] * L2E;     a0[k] = TENL2E - c1[k];
        c1[4 + k] = 0.5f * g1[k] * L2E; a0[4 + k] = TENL2E - c1[4 + k];
    }

    float s8[8];
    #pragma unroll
    for (int k = 0; k < 8; ++k) s8[k] = 0.f;

    #pragma unroll 2
    for (int jt = 0; jt < 8; ++jt) {
        f16x8 v[4];
        #pragma unroll
        for (int u = 0; u < 4; ++u)
            v[u] = *(const f16x8*)(Sn + (size_t)(jb + jt * 32 + u * 8) * SN + i0);
        #pragma unroll
        for (int u = 0; u < 4; ++u)
            #pragma unroll
            for (int k = 0; k < 8; ++k) {
                float arg = fminf(TENL2E, fmaf((float)v[u][k], c1[k], a0[k]));
                s8[k] += exp2f(arg);
            }
    }

    __shared__ float red[8][256];
    #pragma unroll
    for (int k = 0; k < 8; ++k) red[t >> 5][(t & 31) * 8 + k] = s8[k];
    __syncthreads();
    float s = 0.f;
    #pragma unroll
    for (int r = 0; r < 8; ++r) s += red[r][t];
    sumP[((size_t)n * NJC + jc) * SN + ip * 256 + t] = s;
}

// ---------------- streaming pass 2: per-j max over i ----------------
// v2: same 4-way j-batching. Per iter: 4 independent loads, 4 per-j maxes,
// 4 x 32-lane shuffle reduces (i-direction), lane0-of-group writes 4 j's.
__global__ __launch_bounds__(256) void k_colmax(const f16* __restrict__ S,
                                                const float* __restrict__ grow,
                                                const float* __restrict__ alpha,
                                                float* __restrict__ colmaxP) {
    const int n = blockIdx.z, ip = blockIdx.y, jc = blockIdx.x;
    const int t = threadIdx.x;
    const int i0 = ip * 256 + (t & 31) * 8;
    const int jb = jc * 256 + (t >> 5);
    const f16* Sn = S + (size_t)n * SN * SN;

    f32x4 g0 = *(const f32x4*)&grow[(size_t)n * SN + i0];
    f32x4 g1 = *(const f32x4*)&grow[(size_t)n * SN + i0 + 4];
    f32x4 a0 = *(const f32x4*)&alpha[(size_t)n * SN + i0];
    f32x4 a1 = *(const f32x4*)&alpha[(size_t)n * SN + i0 + 4];
    float gk[8], ak[8];
    #pragma unroll
    for (int k = 0; k < 4; ++k) {
        gk[k] = g0[k]; ak[k] = a0[k];
        gk[4 + k] = g1[k]; ak[4 + k] = a1[k];
    }

    float* outRow = colmaxP + ((size_t)n * NIP + ip) * SN;

    #pragma unroll 2
    for (int jt = 0; jt < 8; ++jt) {
        f16x8 v[4];
        #pragma unroll
        for (int u = 0; u < 4; ++u)
            v[u] = *(const f16x8*)(Sn + (size_t)(jb + jt * 32 + u * 8) * SN + i0);
        float m[4];
        #pragma unroll
        for (int u = 0; u < 4; ++u) {
            m[u] = -3.0e38f;
            #pragma unroll
            for (int k = 0; k < 8; ++k) {
                float raw = fmaxf(0.f, fmaf((float)v[u][k], -0.5f, 0.5f));
                m[u] = fmaxf(m[u], fmaf(-gk[k], raw, ak[k]));
            }
        }
        #pragma unroll
        for (int u = 0; u < 4; ++u) {
            #pragma unroll
            for (int d = 1; d < 32; d <<= 1)
                m[u] = fmaxf(m[u], __shfl_xor(m[u], d, 64));
            if ((t & 31) == 0) outRow[jb + jt * 32 + u * 8] = m[u];
        }
    }
}

// ---------------- small reduce kernels ----------------

__global__ __launch_bounds__(256) void r_g(const float* __restrict__ rowmaxP,
                                           float* __restrict__ grow) {
    int idx = blockIdx.x * 256 + threadIdx.x;
    int n = idx / SN, i = idx - n * SN;
    float m = -3.0e38f;
    for (int ch = 0; ch < NCHUNK; ++ch)
        m = fmaxf(m, rowmaxP[(size_t)(n * NCHUNK + ch) * SN + i]);
    float mr = fmaxf(0.f, (1.f - m) * 0.5f);
    grow[idx] = 10.f / (mr + 1e-5f);
}

__global__ __launch_bounds__(256) void r_alpha(const float* __restrict__ rowsumP,
                                               float* __restrict__ alpha, int nch) {
    int idx = blockIdx.x * 256 + threadIdx.x;
    int n = idx / SN, i = idx - n * SN;
    float s = 0.f;
    for (int ch = 0; ch < nch; ++ch)
        s += rowsumP[(size_t)(n * nch + ch) * SN + i];
    alpha[idx] = 10.f - logf(s);
}

__global__ __launch_bounds__(256) void r_colfin(const float* __restrict__ colmaxP,
                                                float* __restrict__ bsum, int nch) {
    int idx = blockIdx.x * 256 + threadIdx.x;
    int n = idx / SN, j = idx - n * SN;
    float m = -3.0e38f;
    for (int ch = 0; ch < nch; ++ch)
        m = fmaxf(m, colmaxP[(size_t)(n * nch + ch) * SN + j]);
    float v = expf(m);
    #pragma unroll
    for (int d = 1; d < 64; d <<= 1) v += __shfl_xor(v, d, 64);
    __shared__ float sb[4];
    if ((threadIdx.x & 63) == 0) sb[threadIdx.x >> 6] = v;
    __syncthreads();
    if (threadIdx.x == 0) bsum[blockIdx.x] = sb[0] + sb[1] + sb[2] + sb[3];
}

__global__ __launch_bounds__(64) void r_loss(const float* __restrict__ bsum,
                                             float* __restrict__ out) {
    int t = threadIdx.x;
    float v = (t < 50) ? bsum[t] : 0.f;
    float v0 = (t < 25) ? v : 0.f;
    float v1 = (t >= 25 && t < 50) ? v : 0.f;
    #pragma unroll
    for (int d = 1; d < 64; d <<= 1) {
        v0 += __shfl_xor(v0, d, 64);
        v1 += __shfl_xor(v1, d, 64);
    }
    if (t == 0) {
        float cs0 = v0 * (1.0f / SN), cs1 = v1 * (1.0f / SN);
        out[0] = -0.5f * (logf(cs0) + logf(cs1));
    }
}

// ---------------- launch ----------------

extern "C" void kernel_launch(void* const* d_in, const int* in_sizes, int n_in,
                              void* d_out, int out_size, void* d_ws, size_t ws_size,
                              hipStream_t stream) {
    const float* I = (const float*)d_in[0];
    const float* T = (const float*)d_in[1];
    float* out = (float*)d_out;

    float* wsf = (float*)d_ws;
    float* meanT = wsf;                         // 256
    float* grow  = meanT + 256;                 // 12800
    float* alpha = grow + 12800;                // 12800
    float* rowmaxP = alpha + 12800;             // 64000 (5 chunks)
    float* sumP  = rowmaxP + 64000;             // 320000 (25 chunks; fallback 5)
    float* colmaxP = sumP + 320000;             // 320000 (25 panels; fallback 5)
    float* bsum = colmaxP + 320000;             // 64
    f16* Ah = (f16*)(bsum + 64);                // 2*6400*256 f16
    f16* Bh = Ah + (size_t)NBATCH * SN * CN;
    f16* Sws = Bh + (size_t)NBATCH * SN * CN;   // 2*6400*6400 f16 = 163.84 MB

    const size_t NEEDED = (size_t)(256 + 12800 + 12800 + 64000
                                   + 320000 + 320000 + 64) * 4
                        + (size_t)2 * NBATCH * SN * CN * 2
                        + (size_t)NBATCH * SN * SN * 2;
    const bool cached = ws_size >= NEEDED;

    k_meanT<<<256, 256, 0, stream>>>(T, meanT);
    k_xpose<<<dim3(100, 8, 2), 256, 0, stream>>>(I, meanT, Ah);
    k_xpose<<<dim3(100, 8, 2), 256, 0, stream>>>(T, meanT, Bh);
    k_nrm<<<3200, 256, 0, stream>>>(Ah, Bh);

    dim3 gg(NTILES, NCHUNK, NBATCH);
    if (cached) {
        k_gemm_s<<<gg, 512, 0, stream>>>(Ah, Bh, rowmaxP, Sws);
        r_g<<<50, 256, 0, stream>>>(rowmaxP, grow);
        k_rowsum<<<dim3(NJC, NIP, NBATCH), 256, 0, stream>>>(Sws, grow, sumP);
        r_alpha<<<50, 256, 0, stream>>>(sumP, alpha, NJC);
        k_colmax<<<dim3(NJC, NIP, NBATCH), 256, 0, stream>>>(Sws, grow, alpha, colmaxP);
        r_colfin<<<50, 256, 0, stream>>>(colmaxP, bsum, NIP);
    } else {
        k_gemm3<0><<<gg, 512, 0, stream>>>(Ah, Bh, nullptr, nullptr, rowmaxP);
        r_g<<<50, 256, 0, stream>>>(rowmaxP, grow);
        k_gemm3<1><<<gg, 512, 0, stream>>>(Ah, Bh, grow, nullptr, sumP);
        r_alpha<<<50, 256, 0, stream>>>(sumP, alpha, NCHUNK);
        k_gemm3<2><<<gg, 512, 0, stream>>>(Bh, Ah, grow, alpha, colmaxP);
        r_colfin<<<50, 256, 0, stream>>>(colmaxP, bsum, NCHUNK);
    }
    r_loss<<<1, 64, 0, stream>>>(bsum, out);
}

// Round 12
// 237.686 us; speedup vs baseline: 1.7151x; 1.0152x over previous
//
#include <hip/hip_runtime.h>

#define SN 6400      // H*W
#define CN 256       // channels (= GEMM K)
#define NBATCH 2
#define NTILES 50    // SN / 128 (fixed-side row tiles, GEMM)
#define NCHUNK 5     // streamed-side chunks (GEMM grid = 50*5*2 = 500 blocks)
#define TPC 5        // 256-wide streamed tiles per chunk
#define NJC 25       // streaming j-chunks (6400/256)
#define NIP 25       // i/j panels of 256

typedef _Float16 f16;
typedef f16 f16x8 __attribute__((ext_vector_type(8)));
typedef f16 f16x4 __attribute__((ext_vector_type(4)));
typedef float f32x4 __attribute__((ext_vector_type(4)));

__device__ __forceinline__ void gld16(const f16* g, f16* l) {
    __builtin_amdgcn_global_load_lds(
        (__attribute__((address_space(1))) void*)(g),
        (__attribute__((address_space(3))) void*)(l), 16, 0, 0);
}

// Stage a 256-row x 64-half (32 KB) K-chunk into LDS with 512 threads
// (4 gld16/thread). XOR source swizzle; verified conflict-free (R0-R11).
__device__ __forceinline__ void stageB(const f16* __restrict__ g,
                                       f16* l, int tid) {
    #pragma unroll
    for (int it = 0; it < 4; ++it) {
        int q = it * 512 + tid;
        int row = q >> 3, c = q & 7;
        int cg = c ^ (row & 7);
        gld16(g + (size_t)row * CN + cg * 8, l + (q & ~63) * 8);
    }
}

// ---------------- prep kernels ----------------

__global__ __launch_bounds__(256) void k_meanT(const float* __restrict__ T,
                                               float* __restrict__ meanT) {
    int c = blockIdx.x, t = threadIdx.x;
    const float* p0 = T + (size_t)c * SN;
    const float* p1 = T + (size_t)(CN + c) * SN;
    float s = 0.f;
    for (int i = t; i < SN; i += 256) s += p0[i] + p1[i];
    #pragma unroll
    for (int d = 1; d < 64; d <<= 1) s += __shfl_xor(s, d, 64);
    __shared__ float sb[4];
    if ((t & 63) == 0) sb[t >> 6] = s;
    __syncthreads();
    if (t == 0) meanT[c] = (sb[0] + sb[1] + sb[2] + sb[3]) * (1.0f / 12800.0f);
}

// FUSED center + transpose + L2-normalize: [n,c,s] f32 -> [n,s,c] f16 unit
// rows. Block = 64 spatial x 256 channels (f32 tile in LDS, pad 66: load &
// sumsq phases bank-conflict-free; write-phase transpose read is 4-way).
// Replaces the old k_xpose + k_nrm pair (saves one full f16 r/w round).
// Sumsq is computed in f32 (pre-rounding) — closer to the f32 reference
// than the old f16-rounded sumsq.
__global__ __launch_bounds__(256) void k_prep(const float* __restrict__ X,
                                              const float* __restrict__ meanT,
                                              f16* __restrict__ out) {
    const int n = blockIdx.z, s0 = blockIdx.x * 64;
    const int t = threadIdx.x, lane = t & 63, w = t >> 6;
    __shared__ float tile[256][66];   // 67.6 KB
    __shared__ float red[64][4];
    __shared__ float rsq[64];

    const float* Xn = X + (size_t)n * CN * SN;
    // load + center: 16 iters x 16 rows; float4 per lane (16 lanes/row)
    #pragma unroll 4
    for (int it = 0; it < 16; ++it) {
        int c = it * 16 + w * 4 + (lane >> 4);
        const float4 v = *(const float4*)&Xn[(size_t)c * SN + s0 + (lane & 15) * 4];
        float mc = meanT[c];
        int col = (lane & 15) * 4;
        tile[c][col + 0] = v.x - mc;
        tile[c][col + 1] = v.y - mc;
        tile[c][col + 2] = v.z - mc;
        tile[c][col + 3] = v.w - mc;
    }
    __syncthreads();
    // per-s sum of squares: thread t -> s = t&63, quarter q = t>>6
    {
        int s = t & 63, q = t >> 6;
        float acc = 0.f;
        #pragma unroll 8
        for (int c = q * 64; c < q * 64 + 64; ++c) {
            float x = tile[c][s];
            acc = fmaf(x, x, acc);
        }
        red[s][q] = acc;
    }
    __syncthreads();
    if (t < 64) rsq[t] = rsqrtf(red[t][0] + red[t][1] + red[t][2] + red[t][3]);
    __syncthreads();
    // write [s][c] f16: wave w handles rows s = w*16 .. w*16+15
    f16* on = out + ((size_t)n * SN + s0) * CN;
    #pragma unroll 4
    for (int r = 0; r < 16; ++r) {
        int s = w * 16 + r;
        float sc = rsq[s];
        int c0 = lane * 4;
        f16x4 hv;
        hv[0] = (f16)(tile[c0 + 0][s] * sc);
        hv[1] = (f16)(tile[c0 + 1][s] * sc);
        hv[2] = (f16)(tile[c0 + 2][s] * sc);
        hv[3] = (f16)(tile[c0 + 3][s] * sc);
        *(f16x4*)(on + (size_t)s * CN + c0) = hv;
    }
}

// ---------------- pass 0: GEMM (R3 structure) + cache S (R11 verbatim) ----
__global__ __launch_bounds__(512, 1) void k_gemm_s(const f16* __restrict__ A,
                                                   const f16* __restrict__ B,
                                                   float* __restrict__ outP,
                                                   f16* __restrict__ Sws) {
    const int n = blockIdx.z, chunk = blockIdx.y, ft = blockIdx.x;
    const int tid = threadIdx.x, lane = tid & 63, wv = tid >> 6;
    const int quad = lane >> 4, lrow = lane & 15;
    const int wr4 = wv >> 2, wc4 = wv & 3;

    __shared__ f16 Abuf[4][128 * 64];   // 64 KB persistent A tile (h-major)
    __shared__ f16 Bb[2][256 * 64];     // 2 x 32 KB double-buffered B stage

    const f16* At = A + ((size_t)n * SN + (size_t)ft * 128) * CN;
    const f16* Bc = B + ((size_t)n * SN + (size_t)chunk * (TPC * 256)) * CN;
    f16* Sn = Sws + (size_t)n * SN * SN;
    const int ibase_th = ft * 128 + wr4 * 64 + quad * 4;

    #pragma unroll
    for (int h = 0; h < 4; ++h) {
        #pragma unroll
        for (int it = 0; it < 2; ++it) {
            int q = it * 512 + tid;
            int row = q >> 3, c = q & 7;
            int cg = c ^ (row & 7);
            gld16(At + (size_t)row * CN + h * 64 + cg * 8,
                  Abuf[h] + (q & ~63) * 8);
        }
    }
    stageB(Bc, Bb[0], tid);
    stageB(Bc + 64, Bb[1], tid);

    int offA[4][2], offB[4][2];
    #pragma unroll
    for (int i = 0; i < 4; ++i) {
        int ra = wr4 * 64 + i * 16 + lrow;
        int rb = wc4 * 64 + i * 16 + lrow;
        #pragma unroll
        for (int kk = 0; kk < 2; ++kk) {
            offA[i][kk] = ra * 64 + (((kk * 4 + quad) ^ (ra & 7)) * 8);
            offB[i][kk] = rb * 64 + (((kk * 4 + quad) ^ (rb & 7)) * 8);
        }
    }

    float runRow[4][4];
    #pragma unroll
    for (int mt = 0; mt < 4; ++mt)
        #pragma unroll
        for (int v = 0; v < 4; ++v) runRow[mt][v] = -3.0e38f;

    asm volatile("s_waitcnt vmcnt(4)" ::: "memory");
    __builtin_amdgcn_s_barrier();

#define BAR()    __builtin_amdgcn_s_barrier()
#define WAIT4()  asm volatile("s_waitcnt vmcnt(4)" ::: "memory")
#define WAIT20() asm volatile("s_waitcnt vmcnt(20)" ::: "memory")
#define WAIT0()  asm volatile("s_waitcnt vmcnt(0)" ::: "memory")

#define STAGE(h, bi)                                                      \
    { _Pragma("unroll")                                                   \
      for (int kk = 0; kk < 2; ++kk) {                                    \
          f16x8 af[4], bf[4];                                             \
          _Pragma("unroll")                                               \
          for (int mt = 0; mt < 4; ++mt)                                  \
              af[mt] = *(const f16x8*)&Abuf[h][offA[mt][kk]];             \
          _Pragma("unroll")                                               \
          for (int nt = 0; nt < 4; ++nt)                                  \
              bf[nt] = *(const f16x8*)&Bb[bi][offB[nt][kk]];              \
          _Pragma("unroll")                                               \
          for (int mt = 0; mt < 4; ++mt)                                  \
              _Pragma("unroll")                                           \
              for (int nt = 0; nt < 4; ++nt)                              \
                  acc[mt][nt] = __builtin_amdgcn_mfma_f32_16x16x32_f16(   \
                      af[mt], bf[nt], acc[mt][nt], 0, 0, 0);              \
      } }

#define EPILOGUE_S(T)                                                     \
    { int jb = (chunk * TPC + (T)) * 256;                                 \
      f16* Sth = Sn + (size_t)(jb + wc4 * 64 + lrow) * SN + ibase_th;     \
      _Pragma("unroll")                                                   \
      for (int mt = 0; mt < 4; ++mt)                                      \
          _Pragma("unroll")                                               \
          for (int nt = 0; nt < 4; ++nt) {                                \
              f16x4 hq;                                                   \
              _Pragma("unroll")                                           \
              for (int v = 0; v < 4; ++v) hq[v] = (f16)acc[mt][nt][v];    \
              *(f16x4*)(Sth + (size_t)nt * 16 * SN + mt * 16) = hq;       \
              _Pragma("unroll")                                           \
              for (int v = 0; v < 4; ++v)                                 \
                  runRow[mt][v] = fmaxf(runRow[mt][v], (float)hq[v]);     \
          } }

    f32x4 acc[4][4];

    #pragma unroll 1
    for (int t = 0; t < TPC - 1; ++t) {
        const f16* Bt = Bc + (size_t)t * (256 * CN);

        #pragma unroll
        for (int mt = 0; mt < 4; ++mt)
            #pragma unroll
            for (int nt = 0; nt < 4; ++nt) acc[mt][nt] = (f32x4){0.f, 0.f, 0.f, 0.f};

        STAGE(0, 0) BAR(); stageB(Bt + 128, Bb[0], tid);
        if (t == 0) { WAIT4(); } else { WAIT20(); }
        BAR();
        STAGE(1, 1) BAR(); stageB(Bt + 192, Bb[1], tid);            WAIT4(); BAR();
        STAGE(2, 0) BAR(); stageB(Bt + 256 * CN, Bb[0], tid);       WAIT4(); BAR();
        STAGE(3, 1) BAR(); stageB(Bt + 256 * CN + 64, Bb[1], tid);
        EPILOGUE_S(t);                                              WAIT20(); BAR();
    }

    {
        const int t = TPC - 1;
        const f16* Bt = Bc + (size_t)t * (256 * CN);

        #pragma unroll
        for (int mt = 0; mt < 4; ++mt)
            #pragma unroll
            for (int nt = 0; nt < 4; ++nt) acc[mt][nt] = (f32x4){0.f, 0.f, 0.f, 0.f};

        STAGE(0, 0) BAR(); stageB(Bt + 128, Bb[0], tid); WAIT20(); BAR();
        STAGE(1, 1) BAR(); stageB(Bt + 192, Bb[1], tid); WAIT4();  BAR();
        STAGE(2, 0) WAIT0(); BAR();
        STAGE(3, 1)
        EPILOGUE_S(t);
    }
#undef STAGE
#undef EPILOGUE_S
#undef BAR
#undef WAIT4
#undef WAIT20
#undef WAIT0

    __syncthreads();
    float* red = (float*)&Bb[0][0];
    #pragma unroll
    for (int mt = 0; mt < 4; ++mt)
        #pragma unroll
        for (int v = 0; v < 4; ++v) {
            float val = runRow[mt][v];
            #pragma unroll
            for (int d = 1; d < 16; d <<= 1)
                val = fmaxf(val, __shfl_xor(val, d, 64));
            if (lrow == 0) red[wc4 * 128 + wr4 * 64 + mt * 16 + quad * 4 + v] = val;
        }
    __syncthreads();
    if (tid < 128) {
        float a = red[tid], b = red[128 + tid];
        float c = red[256 + tid], d = red[384 + tid];
        outP[(size_t)(n * NCHUNK + chunk) * SN + ft * 128 + tid] =
            fmaxf(fmaxf(a, b), fmaxf(c, d));
    }
}

// ---------------- fallback 3-pass GEMM (R3 verbatim) ----------------
template <int PASS>
__global__ __launch_bounds__(512, 2) void k_gemm3(const f16* __restrict__ A,
                                                  const f16* __restrict__ B,
                                                  const float* __restrict__ grow,
                                                  const float* __restrict__ alpha,
                                                  float* __restrict__ outP) {
    const int n = blockIdx.z, chunk = blockIdx.y, ft = blockIdx.x;
    const int tid = threadIdx.x, lane = tid & 63, wv = tid >> 6;
    const int wr = wv >> 2, wc = wv & 3, quad = lane >> 4, lrow = lane & 15;

    __shared__ f16 Abuf[4][128 * 64];
    __shared__ f16 Bb[2][256 * 64];

    const f16* At = A + ((size_t)n * SN + (size_t)ft * 128) * CN;
    const f16* Bc = B + ((size_t)n * SN + (size_t)chunk * (TPC * 256)) * CN;

    const float L2E = 1.44269504089f;
    const float TENL2E = 14.4269504089f;
    float a1c[4][4];
    if constexpr (PASS == 1) {
        #pragma unroll
        for (int mt = 0; mt < 4; ++mt)
            #pragma unroll
            for (int v = 0; v < 4; ++v) {
                int r = ft * 128 + wr * 64 + mt * 16 + quad * 4 + v;
                a1c[mt][v] = 0.5f * grow[(size_t)n * SN + r] * L2E;
            }
    }

    #pragma unroll
    for (int h = 0; h < 4; ++h) {
        #pragma unroll
        for (int it = 0; it < 2; ++it) {
            int q = it * 512 + tid;
            int row = q >> 3, c = q & 7;
            int cg = c ^ (row & 7);
            gld16(At + (size_t)row * CN + h * 64 + cg * 8,
                  Abuf[h] + (q & ~63) * 8);
        }
    }
    stageB(Bc, Bb[0], tid);
    stageB(Bc + 64, Bb[1], tid);

    int offA[4][2], offB[4][2];
    #pragma unroll
    for (int i = 0; i < 4; ++i) {
        int ra = wr * 64 + i * 16 + lrow;
        int rb = wc * 64 + i * 16 + lrow;
        #pragma unroll
        for (int kk = 0; kk < 2; ++kk) {
            offA[i][kk] = ra * 64 + (((kk * 4 + quad) ^ (ra & 7)) * 8);
            offB[i][kk] = rb * 64 + (((kk * 4 + quad) ^ (rb & 7)) * 8);
        }
    }

    float runRow[4][4];
    #pragma unroll
    for (int mt = 0; mt < 4; ++mt)
        #pragma unroll
        for (int v = 0; v < 4; ++v) runRow[mt][v] = (PASS == 1) ? 0.f : -3.0e38f;

    float gl[4], al[4];

    asm volatile("s_waitcnt vmcnt(4)" ::: "memory");
    __builtin_amdgcn_s_barrier();

#define BAR() __builtin_amdgcn_s_barrier()
#define WAIT4() asm volatile("s_waitcnt vmcnt(4)" ::: "memory")
#define WAIT0() asm volatile("s_waitcnt vmcnt(0)" ::: "memory")

#define STAGE(h, bi)                                                      \
    { _Pragma("unroll")                                                   \
      for (int kk = 0; kk < 2; ++kk) {                                    \
          f16x8 af[4], bf[4];                                             \
          _Pragma("unroll")                                               \
          for (int mt = 0; mt < 4; ++mt)                                  \
              af[mt] = *(const f16x8*)&Abuf[h][offA[mt][kk]];             \
          _Pragma("unroll")                                               \
          for (int nt = 0; nt < 4; ++nt)                                  \
              bf[nt] = *(const f16x8*)&Bb[bi][offB[nt][kk]];              \
          _Pragma("unroll")                                               \
          for (int mt = 0; mt < 4; ++mt)                                  \
              _Pragma("unroll")                                           \
              for (int nt = 0; nt < 4; ++nt)                              \
                  acc[mt][nt] = __builtin_amdgcn_mfma_f32_16x16x32_f16(   \
                      af[mt], bf[nt], acc[mt][nt], 0, 0, 0);              \
      } }

#define EPILOGUE()                                                        \
    if constexpr (PASS == 0) {                                            \
        _Pragma("unroll")                                                 \
        for (int mt = 0; mt < 4; ++mt)                                    \
            _Pragma("unroll")                                             \
            for (int v = 0; v < 4; ++v) {                                 \
                float m = fmaxf(fmaxf(acc[mt][0][v], acc[mt][1][v]),      \
                                fmaxf(acc[mt][2][v], acc[mt][3][v]));     \
                runRow[mt][v] = fmaxf(runRow[mt][v], m);                  \
            }                                                             \
    } else if constexpr (PASS == 1) {                                     \
        _Pragma("unroll")                                                 \
        for (int mt = 0; mt < 4; ++mt)                                    \
            _Pragma("unroll")                                             \
            for (int v = 0; v < 4; ++v) {                                 \
                float a1 = a1c[mt][v], a0 = TENL2E - a1;                  \
                float s2 = runRow[mt][v];                                 \
                _Pragma("unroll")                                         \
                for (int nt = 0; nt < 4; ++nt) {                          \
                    float arg = fminf(TENL2E,                             \
                                      fmaf(acc[mt][nt][v], a1, a0));      \
                    s2 += exp2f(arg);                                     \
                }                                                         \
                runRow[mt][v] = s2;                                       \
            }                                                             \
    } else {                                                              \
        _Pragma("unroll")                                                 \
        for (int mt = 0; mt < 4; ++mt)                                    \
            _Pragma("unroll")                                             \
            for (int v = 0; v < 4; ++v) {                                 \
                _Pragma("unroll")                                         \
                for (int nt = 0; nt < 4; ++nt) {                          \
                    float raw = fmaxf(0.f, fmaf(acc[mt][nt][v], -0.5f, 0.5f)); \
                    float lc = fmaf(-gl[nt], raw, al[nt]);                \
                    runRow[mt][v] = fmaxf(runRow[mt][v], lc);             \
                }                                                         \
            }                                                             \
    }

    f32x4 acc[4][4];

    #pragma unroll 1
    for (int t = 0; t < TPC - 1; ++t) {
        const f16* Bt = Bc + (size_t)t * (256 * CN);

        if constexpr (PASS == 2) {
            #pragma unroll
            for (int nt = 0; nt < 4; ++nt) {
                int i = (chunk * TPC + t) * 256 + wc * 64 + nt * 16 + lrow;
                gl[nt] = grow[(size_t)n * SN + i];
                al[nt] = alpha[(size_t)n * SN + i];
            }
        }

        #pragma unroll
        for (int mt = 0; mt < 4; ++mt)
            #pragma unroll
            for (int nt = 0; nt < 4; ++nt) acc[mt][nt] = (f32x4){0.f, 0.f, 0.f, 0.f};

        STAGE(0, 0) BAR(); stageB(Bt + 128, Bb[0], tid);            WAIT4(); BAR();
        STAGE(1, 1) BAR(); stageB(Bt + 192, Bb[1], tid);            WAIT4(); BAR();
        STAGE(2, 0) BAR(); stageB(Bt + 256 * CN, Bb[0], tid);       WAIT4(); BAR();
        STAGE(3, 1) BAR(); stageB(Bt + 256 * CN + 64, Bb[1], tid);
        EPILOGUE();                                                 WAIT4(); BAR();
    }

    {
        const int t = TPC - 1;
        const f16* Bt = Bc + (size_t)t * (256 * CN);

        if constexpr (PASS == 2) {
            #pragma unroll
            for (int nt = 0; nt < 4; ++nt) {
                int i = (chunk * TPC + t) * 256 + wc * 64 + nt * 16 + lrow;
                gl[nt] = grow[(size_t)n * SN + i];
                al[nt] = alpha[(size_t)n * SN + i];
            }
        }

        #pragma unroll
        for (int mt = 0; mt < 4; ++mt)
            #pragma unroll
            for (int nt = 0; nt < 4; ++nt) acc[mt][nt] = (f32x4){0.f, 0.f, 0.f, 0.f};

        STAGE(0, 0) BAR(); stageB(Bt + 128, Bb[0], tid); WAIT4(); BAR();
        STAGE(1, 1) BAR(); stageB(Bt + 192, Bb[1], tid); WAIT4(); BAR();
        STAGE(2, 0) WAIT0(); BAR();
        STAGE(3, 1)
        EPILOGUE();
    }
#undef STAGE
#undef EPILOGUE
#undef BAR
#undef WAIT4
#undef WAIT0

    __syncthreads();
    float* red = (float*)&Bb[0][0];
    #pragma unroll
    for (int mt = 0; mt < 4; ++mt)
        #pragma unroll
        for (int v = 0; v < 4; ++v) {
            float val = runRow[mt][v];
            #pragma unroll
            for (int d = 1; d < 16; d <<= 1) {
                float o = __shfl_xor(val, d, 64);
                val = (PASS == 1) ? (val + o) : fmaxf(val, o);
            }
            if (lrow == 0) red[wc * 128 + wr * 64 + mt * 16 + quad * 4 + v] = val;
        }
    __syncthreads();
    if (tid < 128) {
        float a = red[tid], b = red[128 + tid];
        float c = red[256 + tid], d = red[384 + tid];
        float r = (PASS == 1) ? (a + b + c + d)
                              : fmaxf(fmaxf(a, b), fmaxf(c, d));
        outP[(size_t)(n * NCHUNK + chunk) * SN + ft * 128 + tid] = r;
    }
}

// ---------------- streaming pass 1: per-i sum of exp over j ----------------
// v3: 8-way j-batched loads (128 B in flight/thread). 4 iters x 64 j.
__global__ __launch_bounds__(256) void k_rowsum(const f16* __restrict__ S,
                                                const float* __restrict__ grow,
                                                float* __restrict__ sumP) {
    const int n = blockIdx.z, ip = blockIdx.y, jc = blockIdx.x;
    const int t = threadIdx.x;
    const int i0 = ip * 256 + (t & 31) * 8;
    const int jb = jc * 256 + (t >> 5);
    const f16* Sn = S + (size_t)n * SN * SN;
    const float L2E = 1.44269504089f;
    const float TENL2E = 14.4269504089f;

    f32x4 g0 = *(const f32x4*)&grow[(size_t)n * SN + i0];
    f32x4 g1 = *(const f32x4*)&grow[(size_t)n * SN + i0 + 4];
    float c1[8], a0[8];
    #pragma unroll
    for (int k = 0; k < 4; ++k) {
        c1[k] = 0.5f * g0[k] * L2E;     a0[k] = TENL2E - c1[k];
        c1[4 + k] = 0.5f * g1[k] * L2E; a0[4 + k] = TENL2E - c1[4 + k];
    }

    float s8[8];
    #pragma unroll
    for (int k = 0; k < 8; ++k) s8[k] = 0.f;

    #pragma unroll 1
    for (int jt = 0; jt < 4; ++jt) {
        f16x8 v[8];
        #pragma unroll
        for (int u = 0; u < 8; ++u)
            v[u] = *(const f16x8*)(Sn + (size_t)(jb + jt * 64 + u * 8) * SN + i0);
        #pragma unroll
        for (int u = 0; u < 8; ++u)
            #pragma unroll
            for (int k = 0; k < 8; ++k) {
                float arg = fminf(TENL2E, fmaf((float)v[u][k], c1[k], a0[k]));
                s8[k] += exp2f(arg);
            }
    }

    __shared__ float red[8][256];
    #pragma unroll
    for (int k = 0; k < 8; ++k) red[t >> 5][(t & 31) * 8 + k] = s8[k];
    __syncthreads();
    float s = 0.f;
    #pragma unroll
    for (int r = 0; r < 8; ++r) s += red[r][t];
    sumP[((size_t)n * NJC + jc) * SN + ip * 256 + t] = s;
}

// ---------------- streaming pass 2: per-j max over i ----------------
// v3: 8-way j-batched loads; shuffle tree replaced by LDS-batched reduce
// (cmx[256][33]: stride-1 writes and (t+k)%32 reads are conflict-free; 64
// ds ops/thread, no serial shuffle chains — v2 had 160 shfl with 5-deep
// dependent chains).
__global__ __launch_bounds__(256) void k_colmax(const f16* __restrict__ S,
                                                const float* __restrict__ grow,
                                                const float* __restrict__ alpha,
                                                float* __restrict__ colmaxP) {
    const int n = blockIdx.z, ip = blockIdx.y, jc = blockIdx.x;
    const int t = threadIdx.x;
    const int i0 = ip * 256 + (t & 31) * 8;
    const int jb = jc * 256 + (t >> 5);
    const f16* Sn = S + (size_t)n * SN * SN;

    __shared__ float cmx[256][33];   // 33.8 KB

    f32x4 g0 = *(const f32x4*)&grow[(size_t)n * SN + i0];
    f32x4 g1 = *(const f32x4*)&grow[(size_t)n * SN + i0 + 4];
    f32x4 a0 = *(const f32x4*)&alpha[(size_t)n * SN + i0];
    f32x4 a1 = *(const f32x4*)&alpha[(size_t)n * SN + i0 + 4];
    float gk[8], ak[8];
    #pragma unroll
    for (int k = 0; k < 4; ++k) {
        gk[k] = g0[k]; ak[k] = a0[k];
        gk[4 + k] = g1[k]; ak[4 + k] = a1[k];
    }

    #pragma unroll 1
    for (int jt = 0; jt < 4; ++jt) {
        f16x8 v[8];
        #pragma unroll
        for (int u = 0; u < 8; ++u)
            v[u] = *(const f16x8*)(Sn + (size_t)(jb + jt * 64 + u * 8) * SN + i0);
        #pragma unroll
        for (int u = 0; u < 8; ++u) {
            float m = -3.0e38f;
            #pragma unroll
            for (int k = 0; k < 8; ++k) {
                float raw = fmaxf(0.f, fmaf((float)v[u][k], -0.5f, 0.5f));
                m = fmaxf(m, fmaf(-gk[k], raw, ak[k]));
            }
            cmx[jt * 64 + u * 8 + (t >> 5)][t & 31] = m;
        }
    }
    __syncthreads();

    // thread t owns local j = t: max over 32 i-group partials
    float m = -3.0e38f;
    #pragma unroll 8
    for (int k = 0; k < 32; ++k) m = fmaxf(m, cmx[t][k]);
    colmaxP[((size_t)n * NIP + ip) * SN + jc * 256 + t] = m;
}

// ---------------- small reduce kernels ----------------

__global__ __launch_bounds__(256) void r_g(const float* __restrict__ rowmaxP,
                                           float* __restrict__ grow) {
    int idx = blockIdx.x * 256 + threadIdx.x;
    int n = idx / SN, i = idx - n * SN;
    float m = -3.0e38f;
    for (int ch = 0; ch < NCHUNK; ++ch)
        m = fmaxf(m, rowmaxP[(size_t)(n * NCHUNK + ch) * SN + i]);
    float mr = fmaxf(0.f, (1.f - m) * 0.5f);
    grow[idx] = 10.f / (mr + 1e-5f);
}

__global__ __launch_bounds__(256) void r_alpha(const float* __restrict__ rowsumP,
                                               float* __restrict__ alpha, int nch) {
    int idx = blockIdx.x * 256 + threadIdx.x;
    int n = idx / SN, i = idx - n * SN;
    float s = 0.f;
    for (int ch = 0; ch < nch; ++ch)
        s += rowsumP[(size_t)(n * nch + ch) * SN + i];
    alpha[idx] = 10.f - logf(s);
}

__global__ __launch_bounds__(256) void r_colfin(const float* __restrict__ colmaxP,
                                                float* __restrict__ bsum, int nch) {
    int idx = blockIdx.x * 256 + threadIdx.x;
    int n = idx / SN, j = idx - n * SN;
    float m = -3.0e38f;
    for (int ch = 0; ch < nch; ++ch)
        m = fmaxf(m, colmaxP[(size_t)(n * nch + ch) * SN + j]);
    float v = expf(m);
    #pragma unroll
    for (int d = 1; d < 64; d <<= 1) v += __shfl_xor(v, d, 64);
    __shared__ float sb[4];
    if ((threadIdx.x & 63) == 0) sb[threadIdx.x >> 6] = v;
    __syncthreads();
    if (threadIdx.x == 0) bsum[blockIdx.x] = sb[0] + sb[1] + sb[2] + sb[3];
}

__global__ __launch_bounds__(64) void r_loss(const float* __restrict__ bsum,
                                             float* __restrict__ out) {
    int t = threadIdx.x;
    float v = (t < 50) ? bsum[t] : 0.f;
    float v0 = (t < 25) ? v : 0.f;
    float v1 = (t >= 25 && t < 50) ? v : 0.f;
    #pragma unroll
    for (int d = 1; d < 64; d <<= 1) {
        v0 += __shfl_xor(v0, d, 64);
        v1 += __shfl_xor(v1, d, 64);
    }
    if (t == 0) {
        float cs0 = v0 * (1.0f / SN), cs1 = v1 * (1.0f / SN);
        out[0] = -0.5f * (logf(cs0) + logf(cs1));
    }
}

// ---------------- launch ----------------

extern "C" void kernel_launch(void* const* d_in, const int* in_sizes, int n_in,
                              void* d_out, int out_size, void* d_ws, size_t ws_size,
                              hipStream_t stream) {
    const float* I = (const float*)d_in[0];
    const float* T = (const float*)d_in[1];
    float* out = (float*)d_out;

    float* wsf = (float*)d_ws;
    float* meanT = wsf;                         // 256
    float* grow  = meanT + 256;                 // 12800
    float* alpha = grow + 12800;                // 12800
    float* rowmaxP = alpha + 12800;             // 64000 (5 chunks)
    float* sumP  = rowmaxP + 64000;             // 320000 (25 chunks; fallback 5)
    float* colmaxP = sumP + 320000;             // 320000 (25 panels; fallback 5)
    float* bsum = colmaxP + 320000;             // 64
    f16* Ah = (f16*)(bsum + 64);                // 2*6400*256 f16
    f16* Bh = Ah + (size_t)NBATCH * SN * CN;
    f16* Sws = Bh + (size_t)NBATCH * SN * CN;   // 2*6400*6400 f16 = 163.84 MB

    const size_t NEEDED = (size_t)(256 + 12800 + 12800 + 64000
                                   + 320000 + 320000 + 64) * 4
                        + (size_t)2 * NBATCH * SN * CN * 2
                        + (size_t)NBATCH * SN * SN * 2;
    const bool cached = ws_size >= NEEDED;

    k_meanT<<<256, 256, 0, stream>>>(T, meanT);
    k_prep<<<dim3(100, 1, 2), 256, 0, stream>>>(I, meanT, Ah);
    k_prep<<<dim3(100, 1, 2), 256, 0, stream>>>(T, meanT, Bh);

    dim3 gg(NTILES, NCHUNK, NBATCH);
    if (cached) {
        k_gemm_s<<<gg, 512, 0, stream>>>(Ah, Bh, rowmaxP, Sws);
        r_g<<<50, 256, 0, stream>>>(rowmaxP, grow);
        k_rowsum<<<dim3(NJC, NIP, NBATCH), 256, 0, stream>>>(Sws, grow, sumP);
        r_alpha<<<50, 256, 0, stream>>>(sumP, alpha, NJC);
        k_colmax<<<dim3(NJC, NIP, NBATCH), 256, 0, stream>>>(Sws, grow, alpha, colmaxP);
        r_colfin<<<50, 256, 0, stream>>>(colmaxP, bsum, NIP);
    } else {
        k_gemm3<0><<<gg, 512, 0, stream>>>(Ah, Bh, nullptr, nullptr, rowmaxP);
        r_g<<<50, 256, 0, stream>>>(rowmaxP, grow);
        k_gemm3<1><<<gg, 512, 0, stream>>>(Ah, Bh, grow, nullptr, sumP);
        r_alpha<<<50, 256, 0, stream>>>(sumP, alpha, NCHUNK);
        k_gemm3<2><<<gg, 512, 0, stream>>>(Bh, Ah, grow, alpha, colmaxP);
        r_colfin<<<50, 256, 0, stream>>>(colmaxP, bsum, NCHUNK);
    }
    r_loss<<<1, 64, 0, stream>>>(bsum, out);
}